// Round 1
// baseline (3791.109 us; speedup 1.0000x reference)
//
#include <hip/hip_runtime.h>
#include <hip/hip_bf16.h>
#include <math.h>

#define DM 256
#define NHEAD 8
#define HD 32
#define NL 4
#define BATCH 8
#define SEQ 4096
#define KCLS 10
#define M_TOK (BATCH*SEQ)   // 32768

__device__ __forceinline__ float wave_reduce_sum(float v) {
    #pragma unroll
    for (int off = 32; off > 0; off >>= 1) v += __shfl_xor(v, off, 64);
    return v;
}

// ---------------- copy feat -> x (d_out) ----------------
__global__ void copy_f4(const float4* __restrict__ src, float4* __restrict__ dst, int n4) {
    int i = blockIdx.x * blockDim.x + threadIdx.x;
    if (i < n4) dst[i] = src[i];
}

// ---------------- routing: seg[b,l] = argmax_k cos(fc[b,k], x[b,l]) ----------------
__global__ void route_kernel(const float* __restrict__ x, const float* __restrict__ fc,
                             int* __restrict__ seg) {
    int wid = (int)((blockIdx.x * (size_t)blockDim.x + threadIdx.x) >> 6);  // one wave per token
    int lane = threadIdx.x & 63;
    if (wid >= M_TOK) return;
    int b = wid / SEQ;
    float4 xv = *(const float4*)(x + (size_t)wid * DM + lane * 4);
    float nb2 = xv.x*xv.x + xv.y*xv.y + xv.z*xv.z + xv.w*xv.w;
    nb2 = wave_reduce_sum(nb2);
    float nb = sqrtf(nb2);
    float best = -1e30f; int bestk = 0;
    for (int k = 0; k < KCLS; ++k) {
        float4 fv = *(const float4*)(fc + ((size_t)(b * KCLS + k)) * DM + lane * 4);
        float d = fv.x*xv.x + fv.y*xv.y + fv.z*xv.z + fv.w*xv.w;
        float n = fv.x*fv.x + fv.y*fv.y + fv.z*fv.z + fv.w*fv.w;
        d = wave_reduce_sum(d);
        n = wave_reduce_sum(n);
        float sim = d / fmaxf(sqrtf(n) * nb, 1e-8f);
        if (sim > best) { best = sim; bestk = k; }
    }
    if (lane == 0) seg[wid] = bestk;
}

// ---------------- tiled fp32 GEMM  out[m,n] = act( sum_k A[m,k] W[k,n] ) ----------------
// A is [M, KDIM] given as A0 (k<256) and A1 (k>=256), each row-stride 256.
// Output column n<256 -> O0, n>=256 -> O1, each row-stride 256.
// ACT: 0 none, 1 elu+1, 2 relu.
template<int KDIM, int ACT>
__global__ __launch_bounds__(256) void gemm_kernel(
    const float* __restrict__ A0, const float* __restrict__ A1,
    const float* __restrict__ W, int N,
    float* __restrict__ O0, float* __restrict__ O1)
{
    __shared__ float As[16][64];   // [k][m]
    __shared__ float Ws[16][64];   // [k][n]
    int bm = blockIdx.x * 64;
    int bn = blockIdx.y * 64;
    int t = threadIdx.x;
    int tx = t & 15, ty = t >> 4;
    int arow = t >> 2, akq = (t & 3) * 4;
    int wrow = t >> 4, wnq = (t & 15) * 4;
    float acc[4][4] = {};
    for (int k0 = 0; k0 < KDIM; k0 += 16) {
        const float* Ab = (KDIM == 512 && k0 >= 256) ? A1 : A0;
        int kk0 = k0 & 255;
        float4 av = *(const float4*)(Ab + (size_t)(bm + arow) * 256 + kk0 + akq);
        As[akq + 0][arow] = av.x; As[akq + 1][arow] = av.y;
        As[akq + 2][arow] = av.z; As[akq + 3][arow] = av.w;
        *(float4*)&Ws[wrow][wnq] = *(const float4*)(W + (size_t)(k0 + wrow) * N + bn + wnq);
        __syncthreads();
        #pragma unroll
        for (int kk = 0; kk < 16; ++kk) {
            float4 a  = *(const float4*)&As[kk][ty * 4];
            float4 bv = *(const float4*)&Ws[kk][tx * 4];
            float ar[4] = {a.x, a.y, a.z, a.w};
            float br[4] = {bv.x, bv.y, bv.z, bv.w};
            #pragma unroll
            for (int i = 0; i < 4; ++i)
                #pragma unroll
                for (int j = 0; j < 4; ++j)
                    acc[i][j] = fmaf(ar[i], br[j], acc[i][j]);
        }
        __syncthreads();
    }
    int n0 = bn + tx * 4;
    float* Ob = (n0 < 256) ? O0 : O1;
    int nn = n0 & 255;
    #pragma unroll
    for (int i = 0; i < 4; ++i) {
        float vals[4];
        #pragma unroll
        for (int j = 0; j < 4; ++j) {
            float v = acc[i][j];
            if (ACT == 1) v = (v > 0.f) ? v + 1.f : expf(v);   // elu(x)+1
            else if (ACT == 2) v = fmaxf(v, 0.f);              // relu
            vals[j] = v;
        }
        float4 o; o.x = vals[0]; o.y = vals[1]; o.z = vals[2]; o.w = vals[3];
        *(float4*)(Ob + (size_t)(bm + ty * 4 + i) * 256 + nn) = o;
    }
}

// ---------------- KV / Ksum segment reduction ----------------
// KV[b,c,h,d,e] = sum_{l in cluster c} Kf[b,l,h,d] * V[b,l,h,e]
// Ks[b,c,h,d]   = sum_{l in cluster c} Kf[b,l,h,d]
#define KVTOK 8
#define KVSEG 4
__global__ __launch_bounds__(256) void kv_kernel(
    const float* __restrict__ Kf, const float* __restrict__ V,
    const int* __restrict__ seg, float* __restrict__ KV, float* __restrict__ Ks)
{
    int blk = blockIdx.x;
    int s = blk & (KVSEG - 1);
    int bh = blk / KVSEG;
    int b = bh >> 3, h = bh & 7;
    int t = threadIdx.x;
    int d = t >> 3, e0 = (t & 7) * 4;
    __shared__ float sK[KVTOK][32];
    __shared__ float sV[KVTOK][32];
    __shared__ int sSeg[KVTOK];
    float4 a0 = {0,0,0,0}, a1 = a0, a2 = a0, a3 = a0, a4 = a0;
    float4 a5 = a0, a6 = a0, a7 = a0, a8 = a0, a9 = a0;
    float ks0 = 0, ks1 = 0, ks2 = 0, ks3 = 0, ks4 = 0;
    float ks5 = 0, ks6 = 0, ks7 = 0, ks8 = 0, ks9 = 0;
    int ltok = t >> 5, lj = t & 31;
    const int lbeg = s * (SEQ / KVSEG), lend = lbeg + (SEQ / KVSEG);
    for (int l = lbeg; l < lend; l += KVTOK) {
        size_t gbase = ((size_t)(b * SEQ + l + ltok)) * DM + h * HD + lj;
        sK[ltok][lj] = Kf[gbase];
        sV[ltok][lj] = V[gbase];
        if (t < KVTOK) sSeg[t] = seg[b * SEQ + l + t];
        __syncthreads();
        #pragma unroll
        for (int tok = 0; tok < KVTOK; ++tok) {
            int c = sSeg[tok];                         // block-uniform
            float kd = sK[tok][d];
            float4 v = *(const float4*)&sV[tok][e0];
            switch (c) {
            #define ACC_CASE(n) case n: \
                a##n.x = fmaf(kd, v.x, a##n.x); a##n.y = fmaf(kd, v.y, a##n.y); \
                a##n.z = fmaf(kd, v.z, a##n.z); a##n.w = fmaf(kd, v.w, a##n.w); \
                ks##n += kd; break;
            ACC_CASE(0) ACC_CASE(1) ACC_CASE(2) ACC_CASE(3) ACC_CASE(4)
            ACC_CASE(5) ACC_CASE(6) ACC_CASE(7) ACC_CASE(8) ACC_CASE(9)
            #undef ACC_CASE
            }
        }
        __syncthreads();
    }
    #define WRITE_C(n) { \
        float* p = KV + (((size_t)(b * KCLS + n) * NHEAD + h) * HD + d) * HD + e0; \
        atomicAdd(p + 0, a##n.x); atomicAdd(p + 1, a##n.y); \
        atomicAdd(p + 2, a##n.z); atomicAdd(p + 3, a##n.w); \
        if ((t & 7) == 0) atomicAdd(Ks + ((size_t)(b * KCLS + n) * NHEAD + h) * HD + d, ks##n); }
    WRITE_C(0) WRITE_C(1) WRITE_C(2) WRITE_C(3) WRITE_C(4)
    WRITE_C(5) WRITE_C(6) WRITE_C(7) WRITE_C(8) WRITE_C(9)
    #undef WRITE_C
}

// ---------------- per-token message: Q <- (Q . KV[seg]) / (Q . Ksum[seg] + eps) ----------------
__global__ __launch_bounds__(256) void msg_kernel(
    float* __restrict__ Q, const float* __restrict__ KV,
    const float* __restrict__ Ks, const int* __restrict__ seg)
{
    int tokn = blockIdx.x;
    int b = tokn / SEQ;
    int t = threadIdx.x;
    int h = t >> 5, e = t & 31;
    __shared__ float sQ[DM];
    sQ[t] = Q[(size_t)tokn * DM + t];
    __syncthreads();
    int c = seg[tokn];
    const float* kvp = KV + ((size_t)(b * KCLS + c) * NHEAD + h) * HD * HD;
    const float* ksp = Ks + ((size_t)(b * KCLS + c) * NHEAD + h) * HD;
    float macc = 0.f, zacc = 0.f;
    #pragma unroll
    for (int dd = 0; dd < 32; ++dd) {
        float qd = sQ[h * 32 + dd];
        macc = fmaf(qd, kvp[dd * 32 + e], macc);
        zacc = fmaf(qd, ksp[dd], zacc);
    }
    Q[(size_t)tokn * DM + t] = macc / (zacc + 1e-6f);
}

// ---------------- LayerNorm over last dim 256 (wave per row); optional fused residual add ----------------
__global__ __launch_bounds__(256) void ln_kernel(
    float* __restrict__ buf, const float* __restrict__ g, const float* __restrict__ bb,
    float* __restrict__ addTo)
{
    int row = (int)((blockIdx.x * (size_t)blockDim.x + threadIdx.x) >> 6);
    int lane = threadIdx.x & 63;
    if (row >= M_TOK) return;
    float4 x = *(const float4*)(buf + (size_t)row * DM + lane * 4);
    float s  = x.x + x.y + x.z + x.w;
    float s2 = x.x*x.x + x.y*x.y + x.z*x.z + x.w*x.w;
    s  = wave_reduce_sum(s);
    s2 = wave_reduce_sum(s2);
    float mu  = s * (1.f / 256.f);
    float var = s2 * (1.f / 256.f) - mu * mu;
    float rs = rsqrtf(var + 1e-5f);
    float4 gv = *(const float4*)(g + lane * 4);
    float4 bv = *(const float4*)(bb + lane * 4);
    float4 o;
    o.x = gv.x * (x.x - mu) * rs + bv.x;
    o.y = gv.y * (x.y - mu) * rs + bv.y;
    o.z = gv.z * (x.z - mu) * rs + bv.z;
    o.w = gv.w * (x.w - mu) * rs + bv.w;
    if (addTo) {
        float4 cur = *(const float4*)(addTo + (size_t)row * DM + lane * 4);
        cur.x += o.x; cur.y += o.y; cur.z += o.z; cur.w += o.w;
        *(float4*)(addTo + (size_t)row * DM + lane * 4) = cur;
    } else {
        *(float4*)(buf + (size_t)row * DM + lane * 4) = o;
    }
}

extern "C" void kernel_launch(void* const* d_in, const int* in_sizes, int n_in,
                              void* d_out, int out_size, void* d_ws, size_t ws_size,
                              hipStream_t stream)
{
    const float* feat = (const float*)d_in[1];
    const float* fc   = (const float*)d_in[2];
    const float* Wq   = (const float*)d_in[3];
    const float* Wk   = (const float*)d_in[4];
    const float* Wv   = (const float*)d_in[5];
    const float* Wm   = (const float*)d_in[6];
    const float* W1   = (const float*)d_in[7];
    const float* W2   = (const float*)d_in[8];
    const float* g1   = (const float*)d_in[9];
    const float* b1   = (const float*)d_in[10];
    const float* g2   = (const float*)d_in[11];
    const float* b2   = (const float*)d_in[12];
    float* x = (float*)d_out;

    char* ws = (char*)d_ws;
    int* seg = (int*)ws;            ws += (size_t)M_TOK * 4;
    float* KV = (float*)ws;         ws += (size_t)BATCH * KCLS * NHEAD * HD * HD * 4;
    float* Ks = (float*)ws;         ws += (size_t)BATCH * KCLS * NHEAD * HD * 4;
    float* bq = (float*)ws;         ws += (size_t)M_TOK * DM * 4;
    float* bk = (float*)ws;         ws += (size_t)M_TOK * DM * 4;
    float* bv = (float*)ws;         ws += (size_t)M_TOK * DM * 4;

    // x = feat; routing from original feat
    copy_f4<<<8192, 256, 0, stream>>>((const float4*)feat, (float4*)x, M_TOK * DM / 4);
    route_kernel<<<8192, 256, 0, stream>>>(feat, fc, seg);

    dim3 g256(512, 4), g512(512, 8);
    const size_t kvBytes = (size_t)(BATCH * KCLS * NHEAD * HD * HD + BATCH * KCLS * NHEAD * HD) * 4;

    for (int li = 0; li < NL; ++li) {
        const float* wq = Wq + (size_t)li * DM * DM;
        const float* wk = Wk + (size_t)li * DM * DM;
        const float* wv = Wv + (size_t)li * DM * DM;
        const float* wm = Wm + (size_t)li * DM * DM;
        const float* w1 = W1 + (size_t)li * 512 * 512;
        const float* w2 = W2 + (size_t)li * 512 * 256;

        // Q,K,V with elu+1 on Q,K
        gemm_kernel<256, 1><<<g256, 256, 0, stream>>>(x, nullptr, wq, 256, bq, nullptr);
        gemm_kernel<256, 1><<<g256, 256, 0, stream>>>(x, nullptr, wk, 256, bk, nullptr);
        gemm_kernel<256, 0><<<g256, 256, 0, stream>>>(x, nullptr, wv, 256, bv, nullptr);

        hipMemsetAsync(KV, 0, kvBytes, stream);
        kv_kernel<<<BATCH * NHEAD * KVSEG, 256, 0, stream>>>(bk, bv, seg, KV, Ks);

        // bq <- msg (in place)
        msg_kernel<<<M_TOK, 256, 0, stream>>>(bq, KV, Ks, seg);

        // bk <- LN1(msg @ Wm)
        gemm_kernel<256, 0><<<g256, 256, 0, stream>>>(bq, nullptr, wm, 256, bk, nullptr);
        ln_kernel<<<8192, 256, 0, stream>>>(bk, g1 + li * DM, b1 + li * DM, nullptr);

        // h = relu(concat(x, m1) @ W1): cols 0-255 -> bv, 256-511 -> bq
        gemm_kernel<512, 2><<<g512, 256, 0, stream>>>(x, bk, w1, 512, bv, bq);

        // bk <- h @ W2 ; x += LN2(bk)
        gemm_kernel<512, 0><<<g256, 256, 0, stream>>>(bv, bq, w2, 256, bk, nullptr);
        ln_kernel<<<8192, 256, 0, stream>>>(bk, g2 + li * DM, b2 + li * DM, x);
    }
}

// Round 2
// 1761.019 us; speedup vs baseline: 2.1528x; 2.1528x over previous
//
#include <hip/hip_runtime.h>
#include <hip/hip_bf16.h>
#include <math.h>

#define DM 256
#define NHEAD 8
#define HD 32
#define NL 4
#define BATCH 8
#define SEQ 4096
#define KCLS 10
#define M_TOK (BATCH*SEQ)   // 32768

#define BM 128
#define BN 128
#define BKG 64

using bf16x8 = __attribute__((ext_vector_type(8))) short;
using f32x4  = __attribute__((ext_vector_type(4))) float;

__device__ __forceinline__ unsigned short f2bf(float f) {
    __hip_bfloat16 b = __float2bfloat16(f);
    return __builtin_bit_cast(unsigned short, b);
}

__device__ __forceinline__ float wave_reduce_sum(float v) {
    #pragma unroll
    for (int off = 32; off > 0; off >>= 1) v += __shfl_xor(v, off, 64);
    return v;
}

// ---------------- init: x = feat (fp32), xm[:,0:256] = bf16(feat) ----------------
__global__ __launch_bounds__(256) void init_kernel(const float* __restrict__ feat,
                                                   float* __restrict__ x,
                                                   unsigned short* __restrict__ xm) {
    int i = blockIdx.x * 256 + threadIdx.x;      // over M_TOK*64 quads
    int row = i >> 6, c4 = (i & 63) * 4;
    float4 v = *(const float4*)(feat + (size_t)row * DM + c4);
    *(float4*)(x + (size_t)row * DM + c4) = v;
    ushort4 u; u.x = f2bf(v.x); u.y = f2bf(v.y); u.z = f2bf(v.z); u.w = f2bf(v.w);
    *(ushort4*)(xm + (size_t)row * 512 + c4) = u;
}

// ---------------- routing ----------------
__global__ void route_kernel(const float* __restrict__ x, const float* __restrict__ fc,
                             int* __restrict__ seg) {
    int wid = (int)((blockIdx.x * (size_t)blockDim.x + threadIdx.x) >> 6);
    int lane = threadIdx.x & 63;
    if (wid >= M_TOK) return;
    int b = wid / SEQ;
    float4 xv = *(const float4*)(x + (size_t)wid * DM + lane * 4);
    float nb2 = xv.x*xv.x + xv.y*xv.y + xv.z*xv.z + xv.w*xv.w;
    nb2 = wave_reduce_sum(nb2);
    float nb = sqrtf(nb2);
    float best = -1e30f; int bestk = 0;
    for (int k = 0; k < KCLS; ++k) {
        float4 fv = *(const float4*)(fc + ((size_t)(b * KCLS + k)) * DM + lane * 4);
        float d = fv.x*xv.x + fv.y*xv.y + fv.z*xv.z + fv.w*xv.w;
        float n = fv.x*fv.x + fv.y*fv.y + fv.z*fv.z + fv.w*fv.w;
        d = wave_reduce_sum(d);
        n = wave_reduce_sum(n);
        float sim = d / fmaxf(sqrtf(n) * nb, 1e-8f);
        if (sim > best) { best = sim; bestk = k; }
    }
    if (lane == 0) seg[wid] = bestk;
}

// ---------------- weight transpose+convert: src [K][N] fp32 -> dst [N][K] bf16 ----------------
__global__ __launch_bounds__(256) void transpose_bf16(const float* __restrict__ src,
                                                      unsigned short* __restrict__ dst,
                                                      int K, int N) {
    __shared__ float s[64][65];
    int k0 = blockIdx.x * 64, n0 = blockIdx.y * 64;
    int t = threadIdx.x;
    int r = t >> 4, c4 = (t & 15) * 4;
    #pragma unroll
    for (int i = 0; i < 4; ++i) {
        float4 v = *(const float4*)(src + (size_t)(k0 + r + i*16) * N + n0 + c4);
        s[c4+0][r+i*16] = v.x; s[c4+1][r+i*16] = v.y;
        s[c4+2][r+i*16] = v.z; s[c4+3][r+i*16] = v.w;
    }
    __syncthreads();
    #pragma unroll
    for (int i = 0; i < 4; ++i) {
        int nr = r + i*16;
        ushort4 u;
        u.x = f2bf(s[nr][c4+0]); u.y = f2bf(s[nr][c4+1]);
        u.z = f2bf(s[nr][c4+2]); u.w = f2bf(s[nr][c4+3]);
        *(ushort4*)(dst + (size_t)(n0 + nr) * K + k0 + c4) = u;
    }
}

// ---------------- bf16 MFMA GEMM: out = act( A[M,KD] * Bt[N,KD]^T ) ----------------
// MODE 0: fp32 out O0 [M][256] (N=256), no act
// MODE 1: QKV (N=768): cols 0-255 -> O0 (elu+1), 256-511 -> O1 (elu+1), 512-767 -> O2
// MODE 2: W1 (N=512): bf16 out Ob [M][512], relu
template<int KD, int AS, int MODE>
__global__ __launch_bounds__(256) void mfma_gemm(
    const unsigned short* __restrict__ A, const unsigned short* __restrict__ Bt,
    float* __restrict__ O0, float* __restrict__ O1, float* __restrict__ O2,
    unsigned short* __restrict__ Ob)
{
    __shared__ unsigned short As[BM * BKG];
    __shared__ unsigned short Bs[BN * BKG];
    int t = threadIdx.x;
    int lane = t & 63;
    int w = t >> 6;
    int wm = w & 1, wn = w >> 1;         // 2x2 wave grid, each wave 64x64
    int bm = blockIdx.x * BM;
    int bn = blockIdx.y * BN;

    f32x4 acc[4][4];
    #pragma unroll
    for (int m = 0; m < 4; ++m)
        #pragma unroll
        for (int n = 0; n < 4; ++n)
            acc[m][n] = (f32x4){0.f, 0.f, 0.f, 0.f};

    for (int k0 = 0; k0 < KD; k0 += BKG) {
        #pragma unroll
        for (int i = 0; i < 4; ++i) {
            int chunk = i * 256 + t;
            int row = chunk >> 3, cc = chunk & 7;
            __builtin_amdgcn_global_load_lds(
                (const __attribute__((address_space(1))) void*)(A + (size_t)(bm + row) * AS + k0 + cc * 8),
                (__attribute__((address_space(3))) void*)((char*)As + chunk * 16), 16, 0, 0);
            __builtin_amdgcn_global_load_lds(
                (const __attribute__((address_space(1))) void*)(Bt + (size_t)(bn + row) * KD + k0 + cc * 8),
                (__attribute__((address_space(3))) void*)((char*)Bs + chunk * 16), 16, 0, 0);
        }
        asm volatile("s_waitcnt vmcnt(0)");
        __syncthreads();
        #pragma unroll
        for (int kk = 0; kk < 2; ++kk) {
            int kbyte = (kk * 32 + (lane >> 4) * 8) * 2;
            bf16x8 af[4], bfr[4];
            #pragma unroll
            for (int m = 0; m < 4; ++m)
                af[m] = *(const bf16x8*)((const char*)As + (wm*64 + m*16 + (lane & 15)) * 128 + kbyte);
            #pragma unroll
            for (int n = 0; n < 4; ++n)
                bfr[n] = *(const bf16x8*)((const char*)Bs + (wn*64 + n*16 + (lane & 15)) * 128 + kbyte);
            #pragma unroll
            for (int m = 0; m < 4; ++m)
                #pragma unroll
                for (int n = 0; n < 4; ++n)
                    acc[m][n] = __builtin_amdgcn_mfma_f32_16x16x32_bf16(af[m], bfr[n], acc[m][n], 0, 0, 0);
        }
        __syncthreads();
    }

    int row0 = bm + wm * 64 + (lane >> 4) * 4;
    int lcol = wn * 64 + (lane & 15);
    if (MODE == 0) {
        #pragma unroll
        for (int m = 0; m < 4; ++m)
            #pragma unroll
            for (int n = 0; n < 4; ++n)
                #pragma unroll
                for (int j = 0; j < 4; ++j)
                    O0[(size_t)(row0 + m*16 + j) * 256 + bn + lcol + n*16] = acc[m][n][j];
    } else if (MODE == 1) {
        float* Obuf = (bn < 256) ? O0 : (bn < 512) ? O1 : O2;
        const bool act = (bn < 512);
        int cc0 = (bn & 255) + lcol;
        #pragma unroll
        for (int m = 0; m < 4; ++m)
            #pragma unroll
            for (int n = 0; n < 4; ++n)
                #pragma unroll
                for (int j = 0; j < 4; ++j) {
                    float v = acc[m][n][j];
                    if (act) v = (v > 0.f) ? v + 1.f : expf(v);
                    Obuf[(size_t)(row0 + m*16 + j) * 256 + cc0 + n*16] = v;
                }
    } else {
        #pragma unroll
        for (int m = 0; m < 4; ++m)
            #pragma unroll
            for (int n = 0; n < 4; ++n)
                #pragma unroll
                for (int j = 0; j < 4; ++j)
                    Ob[(size_t)(row0 + m*16 + j) * 512 + bn + lcol + n*16] =
                        f2bf(fmaxf(acc[m][n][j], 0.f));
    }
}

// ---------------- KV / Ksum segment reduction (no LDS, prefetched, scalar branch) ----------------
#define KVSEG 16
__global__ __launch_bounds__(256) void kv_kernel(
    const float* __restrict__ Kf, const float* __restrict__ V,
    const int* __restrict__ seg, float* __restrict__ KV, float* __restrict__ Ks)
{
    int blk = blockIdx.x;
    int s = blk & (KVSEG - 1);
    int bh = blk / KVSEG;
    int b = bh >> 3, h = bh & 7;
    int t = threadIdx.x;
    int d = t >> 3, e0 = (t & 7) * 4;
    float4 a0 = {0,0,0,0}, a1 = a0, a2 = a0, a3 = a0, a4 = a0;
    float4 a5 = a0, a6 = a0, a7 = a0, a8 = a0, a9 = a0;
    float ks0 = 0, ks1 = 0, ks2 = 0, ks3 = 0, ks4 = 0;
    float ks5 = 0, ks6 = 0, ks7 = 0, ks8 = 0, ks9 = 0;
    const int lbeg = s * (SEQ / KVSEG), lend = lbeg + (SEQ / KVSEG);
    const float* Kp = Kf + (size_t)(b * SEQ) * DM + h * HD + d;
    const float* Vp = V  + (size_t)(b * SEQ) * DM + h * HD + e0;
    const int* segp = seg + b * SEQ;
    int c = segp[lbeg];
    float kd = Kp[(size_t)lbeg * DM];
    float4 v4 = *(const float4*)(Vp + (size_t)lbeg * DM);
    for (int l = lbeg; l < lend; ++l) {
        int cn = 0; float kdn = 0.f; float4 vn = {0,0,0,0};
        if (l + 1 < lend) {
            cn = segp[l + 1];
            kdn = Kp[(size_t)(l + 1) * DM];
            vn = *(const float4*)(Vp + (size_t)(l + 1) * DM);
        }
        int cs = __builtin_amdgcn_readfirstlane(c);
        switch (cs) {
        #define ACC_CASE(n) case n: \
            a##n.x = fmaf(kd, v4.x, a##n.x); a##n.y = fmaf(kd, v4.y, a##n.y); \
            a##n.z = fmaf(kd, v4.z, a##n.z); a##n.w = fmaf(kd, v4.w, a##n.w); \
            ks##n += kd; break;
        ACC_CASE(0) ACC_CASE(1) ACC_CASE(2) ACC_CASE(3) ACC_CASE(4)
        ACC_CASE(5) ACC_CASE(6) ACC_CASE(7) ACC_CASE(8) ACC_CASE(9)
        #undef ACC_CASE
        }
        c = cn; kd = kdn; v4 = vn;
    }
    #define WRITE_C(n) { \
        float* p = KV + (((size_t)(b * KCLS + n) * NHEAD + h) * HD + d) * HD + e0; \
        atomicAdd(p + 0, a##n.x); atomicAdd(p + 1, a##n.y); \
        atomicAdd(p + 2, a##n.z); atomicAdd(p + 3, a##n.w); \
        if ((t & 7) == 0) atomicAdd(Ks + ((size_t)(b * KCLS + n) * NHEAD + h) * HD + d, ks##n); }
    WRITE_C(0) WRITE_C(1) WRITE_C(2) WRITE_C(3) WRITE_C(4)
    WRITE_C(5) WRITE_C(6) WRITE_C(7) WRITE_C(8) WRITE_C(9)
    #undef WRITE_C
}

// ---------------- per-token message -> bf16 ----------------
__global__ __launch_bounds__(256) void msg_kernel(
    const float* __restrict__ Q, const float* __restrict__ KV,
    const float* __restrict__ Ks, const int* __restrict__ seg,
    unsigned short* __restrict__ msgb)
{
    int tokn = blockIdx.x;
    int b = tokn / SEQ;
    int t = threadIdx.x;
    int h = t >> 5, e = t & 31;
    __shared__ float sQ[DM];
    sQ[t] = Q[(size_t)tokn * DM + t];
    __syncthreads();
    int c = seg[tokn];
    const float* kvp = KV + ((size_t)(b * KCLS + c) * NHEAD + h) * HD * HD;
    const float* ksp = Ks + ((size_t)(b * KCLS + c) * NHEAD + h) * HD;
    float macc = 0.f, zacc = 0.f;
    #pragma unroll
    for (int dd = 0; dd < 32; ++dd) {
        float qd = sQ[h * 32 + dd];
        macc = fmaf(qd, kvp[dd * 32 + e], macc);
        zacc = fmaf(qd, ksp[dd], zacc);
    }
    msgb[(size_t)tokn * DM + t] = f2bf(macc / (zacc + 1e-6f));
}

// ---------------- LN1: bf16 out into xm[:,256:512] ----------------
__global__ __launch_bounds__(256) void ln1_kernel(
    const float* __restrict__ buf, const float* __restrict__ g, const float* __restrict__ bb,
    unsigned short* __restrict__ xm)
{
    int row = (int)((blockIdx.x * (size_t)blockDim.x + threadIdx.x) >> 6);
    int lane = threadIdx.x & 63;
    if (row >= M_TOK) return;
    float4 x = *(const float4*)(buf + (size_t)row * DM + lane * 4);
    float s  = x.x + x.y + x.z + x.w;
    float s2 = x.x*x.x + x.y*x.y + x.z*x.z + x.w*x.w;
    s  = wave_reduce_sum(s);
    s2 = wave_reduce_sum(s2);
    float mu  = s * (1.f / 256.f);
    float var = s2 * (1.f / 256.f) - mu * mu;
    float rs = rsqrtf(var + 1e-5f);
    float4 gv = *(const float4*)(g + lane * 4);
    float4 bv = *(const float4*)(bb + lane * 4);
    ushort4 u;
    u.x = f2bf(gv.x * (x.x - mu) * rs + bv.x);
    u.y = f2bf(gv.y * (x.y - mu) * rs + bv.y);
    u.z = f2bf(gv.z * (x.z - mu) * rs + bv.z);
    u.w = f2bf(gv.w * (x.w - mu) * rs + bv.w);
    *(ushort4*)(xm + (size_t)row * 512 + 256 + lane * 4) = u;
}

// ---------------- LN2: x += ln(buf); xm[:,0:256] = bf16(x) ----------------
__global__ __launch_bounds__(256) void ln2_kernel(
    const float* __restrict__ buf, const float* __restrict__ g, const float* __restrict__ bb,
    float* __restrict__ x, unsigned short* __restrict__ xm)
{
    int row = (int)((blockIdx.x * (size_t)blockDim.x + threadIdx.x) >> 6);
    int lane = threadIdx.x & 63;
    if (row >= M_TOK) return;
    float4 h = *(const float4*)(buf + (size_t)row * DM + lane * 4);
    float s  = h.x + h.y + h.z + h.w;
    float s2 = h.x*h.x + h.y*h.y + h.z*h.z + h.w*h.w;
    s  = wave_reduce_sum(s);
    s2 = wave_reduce_sum(s2);
    float mu  = s * (1.f / 256.f);
    float var = s2 * (1.f / 256.f) - mu * mu;
    float rs = rsqrtf(var + 1e-5f);
    float4 gv = *(const float4*)(g + lane * 4);
    float4 bv = *(const float4*)(bb + lane * 4);
    float4 xv = *(const float4*)(x + (size_t)row * DM + lane * 4);
    xv.x += gv.x * (h.x - mu) * rs + bv.x;
    xv.y += gv.y * (h.y - mu) * rs + bv.y;
    xv.z += gv.z * (h.z - mu) * rs + bv.z;
    xv.w += gv.w * (h.w - mu) * rs + bv.w;
    *(float4*)(x + (size_t)row * DM + lane * 4) = xv;
    ushort4 u; u.x = f2bf(xv.x); u.y = f2bf(xv.y); u.z = f2bf(xv.z); u.w = f2bf(xv.w);
    *(ushort4*)(xm + (size_t)row * 512 + lane * 4) = u;
}

extern "C" void kernel_launch(void* const* d_in, const int* in_sizes, int n_in,
                              void* d_out, int out_size, void* d_ws, size_t ws_size,
                              hipStream_t stream)
{
    const float* feat = (const float*)d_in[1];
    const float* fc   = (const float*)d_in[2];
    const float* Wq   = (const float*)d_in[3];
    const float* Wk   = (const float*)d_in[4];
    const float* Wv   = (const float*)d_in[5];
    const float* Wm   = (const float*)d_in[6];
    const float* W1   = (const float*)d_in[7];
    const float* W2   = (const float*)d_in[8];
    const float* g1   = (const float*)d_in[9];
    const float* b1   = (const float*)d_in[10];
    const float* g2   = (const float*)d_in[11];
    const float* b2   = (const float*)d_in[12];
    float* x = (float*)d_out;

    char* ws = (char*)d_ws;
    auto alloc = [&](size_t bytes) { char* p = ws; ws += (bytes + 255) & ~(size_t)255; return p; };
    int*   seg   = (int*)  alloc((size_t)M_TOK * 4);
    float* KV    = (float*)alloc((size_t)BATCH * KCLS * NHEAD * HD * HD * 4);
    float* Ks    = (float*)alloc((size_t)BATCH * KCLS * NHEAD * HD * 4);
    unsigned short* xm = (unsigned short*)alloc((size_t)M_TOK * 512 * 2);
    char* bufA = alloc((size_t)M_TOK * 512 * 2);   // Q fp32 [M][256] then h bf16 [M][512]
    char* bufB = alloc((size_t)M_TOK * 256 * 4);   // K fp32, then GEMM fp32 outs
    char* bufC = alloc((size_t)M_TOK * 256 * 4);   // V fp32, then msgb bf16
    unsigned short* WqkvT = (unsigned short*)alloc((size_t)NL * 768 * 256 * 2);
    unsigned short* WmT   = (unsigned short*)alloc((size_t)NL * 256 * 256 * 2);
    unsigned short* W1T   = (unsigned short*)alloc((size_t)NL * 512 * 512 * 2);
    unsigned short* W2T   = (unsigned short*)alloc((size_t)NL * 256 * 512 * 2);

    float* Qb = (float*)bufA;
    unsigned short* hb = (unsigned short*)bufA;
    float* Kb = (float*)bufB;
    float* tmp = (float*)bufB;
    float* Vb = (float*)bufC;
    unsigned short* msgb = (unsigned short*)bufC;

    // weight transpose+convert (per launch; small)
    for (int li = 0; li < NL; ++li) {
        transpose_bf16<<<dim3(4, 4), 256, 0, stream>>>(Wq + (size_t)li*65536, WqkvT + (size_t)li*768*256, 256, 256);
        transpose_bf16<<<dim3(4, 4), 256, 0, stream>>>(Wk + (size_t)li*65536, WqkvT + (size_t)li*768*256 + 65536, 256, 256);
        transpose_bf16<<<dim3(4, 4), 256, 0, stream>>>(Wv + (size_t)li*65536, WqkvT + (size_t)li*768*256 + 131072, 256, 256);
        transpose_bf16<<<dim3(4, 4), 256, 0, stream>>>(Wm + (size_t)li*65536, WmT + (size_t)li*65536, 256, 256);
        transpose_bf16<<<dim3(8, 8), 256, 0, stream>>>(W1 + (size_t)li*262144, W1T + (size_t)li*262144, 512, 512);
        transpose_bf16<<<dim3(8, 4), 256, 0, stream>>>(W2 + (size_t)li*131072, W2T + (size_t)li*131072, 512, 256);
    }

    init_kernel<<<8192, 256, 0, stream>>>(feat, x, xm);
    route_kernel<<<8192, 256, 0, stream>>>(feat, fc, seg);

    const size_t kvBytes = (size_t)(BATCH * KCLS * NHEAD * HD * HD + BATCH * KCLS * NHEAD * HD) * 4;

    for (int li = 0; li < NL; ++li) {
        const unsigned short* wqkv = WqkvT + (size_t)li * 768 * 256;
        const unsigned short* wm   = WmT + (size_t)li * 65536;
        const unsigned short* w1   = W1T + (size_t)li * 262144;
        const unsigned short* w2   = W2T + (size_t)li * 131072;

        // Q,K (elu+1) and V : one fused GEMM, N=768
        mfma_gemm<256, 512, 1><<<dim3(256, 6), 256, 0, stream>>>(xm, wqkv, Qb, Kb, Vb, nullptr);

        hipMemsetAsync(KV, 0, kvBytes, stream);
        kv_kernel<<<BATCH * NHEAD * KVSEG, 256, 0, stream>>>(Kb, Vb, seg, KV, Ks);

        // msgb (bf16) <- attention message
        msg_kernel<<<M_TOK, 256, 0, stream>>>(Qb, KV, Ks, seg, msgb);

        // tmp <- msg @ Wm ; xm[:,256:512] <- bf16(LN1(tmp))
        mfma_gemm<256, 256, 0><<<dim3(256, 2), 256, 0, stream>>>(msgb, wm, tmp, nullptr, nullptr, nullptr);
        ln1_kernel<<<8192, 256, 0, stream>>>(tmp, g1 + li * DM, b1 + li * DM, xm);

        // hb (bf16 [M][512]) <- relu(concat(x,m1) @ W1)
        mfma_gemm<512, 512, 2><<<dim3(256, 4), 256, 0, stream>>>(xm, w1, nullptr, nullptr, nullptr, hb);

        // tmp <- h @ W2 ; x += LN2(tmp); xm[:,0:256] <- bf16(x)
        mfma_gemm<512, 512, 0><<<dim3(256, 2), 256, 0, stream>>>(hb, w2, tmp, nullptr, nullptr, nullptr);
        ln2_kernel<<<8192, 256, 0, stream>>>(tmp, g2 + li * DM, b2 + li * DM, x, xm);
    }
}

// Round 3
// 1681.223 us; speedup vs baseline: 2.2550x; 1.0475x over previous
//
#include <hip/hip_runtime.h>
#include <hip/hip_bf16.h>
#include <math.h>

#define DM 256
#define NHEAD 8
#define HD 32
#define NL 4
#define BATCH 8
#define SEQ 4096
#define KCLS 10
#define M_TOK (BATCH*SEQ)   // 32768

#define BM 128
#define BN 128
#define BKG 64

#define KVSEG 8
#define PART_STRIDE (KCLS * 1056)   // per-block partial: 10 clusters x (1024 KV + 32 Ks)

using bf16x8 = __attribute__((ext_vector_type(8))) short;
using f32x4  = __attribute__((ext_vector_type(4))) float;

__device__ __forceinline__ unsigned short f2bf(float f) {
    __hip_bfloat16 b = __float2bfloat16(f);
    return __builtin_bit_cast(unsigned short, b);
}

__device__ __forceinline__ float wave_reduce_sum(float v) {
    #pragma unroll
    for (int off = 32; off > 0; off >>= 1) v += __shfl_xor(v, off, 64);
    return v;
}

// ---------------- init: x = feat (fp32), xm[:,0:256] = bf16(feat) ----------------
__global__ __launch_bounds__(256) void init_kernel(const float* __restrict__ feat,
                                                   float* __restrict__ x,
                                                   unsigned short* __restrict__ xm) {
    int i = blockIdx.x * 256 + threadIdx.x;      // over M_TOK*64 quads
    int row = i >> 6, c4 = (i & 63) * 4;
    float4 v = *(const float4*)(feat + (size_t)row * DM + c4);
    *(float4*)(x + (size_t)row * DM + c4) = v;
    ushort4 u; u.x = f2bf(v.x); u.y = f2bf(v.y); u.z = f2bf(v.z); u.w = f2bf(v.w);
    *(ushort4*)(xm + (size_t)row * 512 + c4) = u;
}

// ---------------- routing ----------------
__global__ void route_kernel(const float* __restrict__ x, const float* __restrict__ fc,
                             int* __restrict__ seg) {
    int wid = (int)((blockIdx.x * (size_t)blockDim.x + threadIdx.x) >> 6);
    int lane = threadIdx.x & 63;
    if (wid >= M_TOK) return;
    int b = wid / SEQ;
    float4 xv = *(const float4*)(x + (size_t)wid * DM + lane * 4);
    float nb2 = xv.x*xv.x + xv.y*xv.y + xv.z*xv.z + xv.w*xv.w;
    nb2 = wave_reduce_sum(nb2);
    float nb = sqrtf(nb2);
    float best = -1e30f; int bestk = 0;
    for (int k = 0; k < KCLS; ++k) {
        float4 fv = *(const float4*)(fc + ((size_t)(b * KCLS + k)) * DM + lane * 4);
        float d = fv.x*xv.x + fv.y*xv.y + fv.z*xv.z + fv.w*xv.w;
        float n = fv.x*fv.x + fv.y*fv.y + fv.z*fv.z + fv.w*fv.w;
        d = wave_reduce_sum(d);
        n = wave_reduce_sum(n);
        float sim = d / fmaxf(sqrtf(n) * nb, 1e-8f);
        if (sim > best) { best = sim; bestk = k; }
    }
    if (lane == 0) seg[wid] = bestk;
}

// ---------------- weight transpose+convert: src [K][N] fp32 -> dst [N][K] bf16 ----------------
__global__ __launch_bounds__(256) void transpose_bf16(const float* __restrict__ src,
                                                      unsigned short* __restrict__ dst,
                                                      int K, int N) {
    __shared__ float s[64][65];
    int k0 = blockIdx.x * 64, n0 = blockIdx.y * 64;
    int t = threadIdx.x;
    int r = t >> 4, c4 = (t & 15) * 4;
    #pragma unroll
    for (int i = 0; i < 4; ++i) {
        float4 v = *(const float4*)(src + (size_t)(k0 + r + i*16) * N + n0 + c4);
        s[c4+0][r+i*16] = v.x; s[c4+1][r+i*16] = v.y;
        s[c4+2][r+i*16] = v.z; s[c4+3][r+i*16] = v.w;
    }
    __syncthreads();
    #pragma unroll
    for (int i = 0; i < 4; ++i) {
        int nr = r + i*16;
        ushort4 u;
        u.x = f2bf(s[nr][c4+0]); u.y = f2bf(s[nr][c4+1]);
        u.z = f2bf(s[nr][c4+2]); u.w = f2bf(s[nr][c4+3]);
        *(ushort4*)(dst + (size_t)(n0 + nr) * K + k0 + c4) = u;
    }
}

// ---------------- bf16 MFMA GEMM: out = act( A[M,KD] * Bt[N,KD]^T ) ----------------
// MODE 0: fp32 out O0 [M][256] (N=256), no act
// MODE 1: QKV (N=768): cols 0-255 -> O0 (elu+1), 256-511 -> O1 (elu+1), 512-767 -> O2
// MODE 2: W1 (N=512): bf16 out Ob [M][512], relu
template<int KD, int AS, int MODE>
__global__ __launch_bounds__(256) void mfma_gemm(
    const unsigned short* __restrict__ A, const unsigned short* __restrict__ Bt,
    float* __restrict__ O0, float* __restrict__ O1, float* __restrict__ O2,
    unsigned short* __restrict__ Ob)
{
    __shared__ unsigned short As[BM * BKG];
    __shared__ unsigned short Bs[BN * BKG];
    int t = threadIdx.x;
    int lane = t & 63;
    int w = t >> 6;
    int wm = w & 1, wn = w >> 1;         // 2x2 wave grid, each wave 64x64
    int bm = blockIdx.x * BM;
    int bn = blockIdx.y * BN;

    f32x4 acc[4][4];
    #pragma unroll
    for (int m = 0; m < 4; ++m)
        #pragma unroll
        for (int n = 0; n < 4; ++n)
            acc[m][n] = (f32x4){0.f, 0.f, 0.f, 0.f};

    for (int k0 = 0; k0 < KD; k0 += BKG) {
        #pragma unroll
        for (int i = 0; i < 4; ++i) {
            int chunk = i * 256 + t;
            int row = chunk >> 3, cc = chunk & 7;
            __builtin_amdgcn_global_load_lds(
                (const __attribute__((address_space(1))) void*)(A + (size_t)(bm + row) * AS + k0 + cc * 8),
                (__attribute__((address_space(3))) void*)((char*)As + chunk * 16), 16, 0, 0);
            __builtin_amdgcn_global_load_lds(
                (const __attribute__((address_space(1))) void*)(Bt + (size_t)(bn + row) * KD + k0 + cc * 8),
                (__attribute__((address_space(3))) void*)((char*)Bs + chunk * 16), 16, 0, 0);
        }
        asm volatile("s_waitcnt vmcnt(0)");
        __syncthreads();
        #pragma unroll
        for (int kk = 0; kk < 2; ++kk) {
            int kbyte = (kk * 32 + (lane >> 4) * 8) * 2;
            bf16x8 af[4], bfr[4];
            #pragma unroll
            for (int m = 0; m < 4; ++m)
                af[m] = *(const bf16x8*)((const char*)As + (wm*64 + m*16 + (lane & 15)) * 128 + kbyte);
            #pragma unroll
            for (int n = 0; n < 4; ++n)
                bfr[n] = *(const bf16x8*)((const char*)Bs + (wn*64 + n*16 + (lane & 15)) * 128 + kbyte);
            #pragma unroll
            for (int m = 0; m < 4; ++m)
                #pragma unroll
                for (int n = 0; n < 4; ++n)
                    acc[m][n] = __builtin_amdgcn_mfma_f32_16x16x32_bf16(af[m], bfr[n], acc[m][n], 0, 0, 0);
        }
        __syncthreads();
    }

    int row0 = bm + wm * 64 + (lane >> 4) * 4;
    int lcol = wn * 64 + (lane & 15);
    if (MODE == 0) {
        #pragma unroll
        for (int m = 0; m < 4; ++m)
            #pragma unroll
            for (int n = 0; n < 4; ++n)
                #pragma unroll
                for (int j = 0; j < 4; ++j)
                    O0[(size_t)(row0 + m*16 + j) * 256 + bn + lcol + n*16] = acc[m][n][j];
    } else if (MODE == 1) {
        float* Obuf = (bn < 256) ? O0 : (bn < 512) ? O1 : O2;
        const bool act = (bn < 512);
        int cc0 = (bn & 255) + lcol;
        #pragma unroll
        for (int m = 0; m < 4; ++m)
            #pragma unroll
            for (int n = 0; n < 4; ++n)
                #pragma unroll
                for (int j = 0; j < 4; ++j) {
                    float v = acc[m][n][j];
                    if (act) v = (v > 0.f) ? v + 1.f : expf(v);
                    Obuf[(size_t)(row0 + m*16 + j) * 256 + cc0 + n*16] = v;
                }
    } else {
        #pragma unroll
        for (int m = 0; m < 4; ++m)
            #pragma unroll
            for (int n = 0; n < 4; ++n)
                #pragma unroll
                for (int j = 0; j < 4; ++j)
                    Ob[(size_t)(row0 + m*16 + j) * 512 + bn + lcol + n*16] =
                        f2bf(fmaxf(acc[m][n][j], 0.f));
    }
}

// ---------------- KV / Ksum segment partials (no atomics) ----------------
// part[blk][c][0:1024]   = partial KV (d*32+e)
// part[blk][c][1024:1056] = partial Ksum (d)
__global__ __launch_bounds__(256) void kv_kernel(
    const float* __restrict__ Kf, const float* __restrict__ V,
    const int* __restrict__ seg, float* __restrict__ part)
{
    int blk = blockIdx.x;
    int s = blk & (KVSEG - 1);
    int bh = blk / KVSEG;
    int b = bh >> 3, h = bh & 7;
    int t = threadIdx.x;
    int d = t >> 3, e0 = (t & 7) * 4;
    float4 a0 = {0,0,0,0}, a1 = a0, a2 = a0, a3 = a0, a4 = a0;
    float4 a5 = a0, a6 = a0, a7 = a0, a8 = a0, a9 = a0;
    float ks0 = 0, ks1 = 0, ks2 = 0, ks3 = 0, ks4 = 0;
    float ks5 = 0, ks6 = 0, ks7 = 0, ks8 = 0, ks9 = 0;
    const int lbeg = s * (SEQ / KVSEG), lend = lbeg + (SEQ / KVSEG);
    const float* Kp = Kf + (size_t)(b * SEQ) * DM + h * HD + d;
    const float* Vp = V  + (size_t)(b * SEQ) * DM + h * HD + e0;
    const int* segp = seg + b * SEQ;
    int c = segp[lbeg];
    float kd = Kp[(size_t)lbeg * DM];
    float4 v4 = *(const float4*)(Vp + (size_t)lbeg * DM);
    for (int l = lbeg; l < lend; ++l) {
        int cn = 0; float kdn = 0.f; float4 vn = {0,0,0,0};
        if (l + 1 < lend) {
            cn = segp[l + 1];
            kdn = Kp[(size_t)(l + 1) * DM];
            vn = *(const float4*)(Vp + (size_t)(l + 1) * DM);
        }
        int cs = __builtin_amdgcn_readfirstlane(c);
        switch (cs) {
        #define ACC_CASE(n) case n: \
            a##n.x = fmaf(kd, v4.x, a##n.x); a##n.y = fmaf(kd, v4.y, a##n.y); \
            a##n.z = fmaf(kd, v4.z, a##n.z); a##n.w = fmaf(kd, v4.w, a##n.w); \
            ks##n += kd; break;
        ACC_CASE(0) ACC_CASE(1) ACC_CASE(2) ACC_CASE(3) ACC_CASE(4)
        ACC_CASE(5) ACC_CASE(6) ACC_CASE(7) ACC_CASE(8) ACC_CASE(9)
        #undef ACC_CASE
        }
        c = cn; kd = kdn; v4 = vn;
    }
    float* pb = part + (size_t)blk * PART_STRIDE;
    #define WRITE_C(n) { \
        *(float4*)(pb + n * 1056 + d * 32 + e0) = a##n; \
        if ((t & 7) == 0) pb[n * 1056 + 1024 + d] = ks##n; }
    WRITE_C(0) WRITE_C(1) WRITE_C(2) WRITE_C(3) WRITE_C(4)
    WRITE_C(5) WRITE_C(6) WRITE_C(7) WRITE_C(8) WRITE_C(9)
    #undef WRITE_C
}

// ---------------- reduce partials -> KV, Ks ----------------
__global__ __launch_bounds__(256) void kv_reduce(
    const float* __restrict__ part, float* __restrict__ KV, float* __restrict__ Ks)
{
    int blk = blockIdx.x;          // bh * KCLS + c
    int c = blk % KCLS;
    int bh = blk / KCLS;
    int b = bh >> 3, h = bh & 7;
    int t = threadIdx.x;
    const float* pb = part + (size_t)bh * KVSEG * PART_STRIDE + c * 1056;
    float4 acc = {0, 0, 0, 0};
    float ka = 0.f;
    #pragma unroll
    for (int s = 0; s < KVSEG; ++s) {
        float4 v = *(const float4*)(pb + (size_t)s * PART_STRIDE + t * 4);
        acc.x += v.x; acc.y += v.y; acc.z += v.z; acc.w += v.w;
        if (t < 32) ka += pb[(size_t)s * PART_STRIDE + 1024 + t];
    }
    *(float4*)(KV + ((size_t)(b * KCLS + c) * NHEAD + h) * HD * HD + t * 4) = acc;
    if (t < 32) Ks[((size_t)(b * KCLS + c) * NHEAD + h) * HD + t] = ka;
}

// ---------------- per-token message -> bf16 ----------------
__global__ __launch_bounds__(256) void msg_kernel(
    const float* __restrict__ Q, const float* __restrict__ KV,
    const float* __restrict__ Ks, const int* __restrict__ seg,
    unsigned short* __restrict__ msgb)
{
    int tokn = blockIdx.x;
    int b = tokn / SEQ;
    int t = threadIdx.x;
    int h = t >> 5, e = t & 31;
    __shared__ float sQ[DM];
    sQ[t] = Q[(size_t)tokn * DM + t];
    __syncthreads();
    int c = seg[tokn];
    const float* kvp = KV + ((size_t)(b * KCLS + c) * NHEAD + h) * HD * HD;
    const float* ksp = Ks + ((size_t)(b * KCLS + c) * NHEAD + h) * HD;
    float macc = 0.f, zacc = 0.f;
    #pragma unroll
    for (int dd = 0; dd < 32; ++dd) {
        float qd = sQ[h * 32 + dd];
        macc = fmaf(qd, kvp[dd * 32 + e], macc);
        zacc = fmaf(qd, ksp[dd], zacc);
    }
    msgb[(size_t)tokn * DM + t] = f2bf(macc / (zacc + 1e-6f));
}

// ---------------- LN1: bf16 out into xm[:,256:512] ----------------
__global__ __launch_bounds__(256) void ln1_kernel(
    const float* __restrict__ buf, const float* __restrict__ g, const float* __restrict__ bb,
    unsigned short* __restrict__ xm)
{
    int row = (int)((blockIdx.x * (size_t)blockDim.x + threadIdx.x) >> 6);
    int lane = threadIdx.x & 63;
    if (row >= M_TOK) return;
    float4 x = *(const float4*)(buf + (size_t)row * DM + lane * 4);
    float s  = x.x + x.y + x.z + x.w;
    float s2 = x.x*x.x + x.y*x.y + x.z*x.z + x.w*x.w;
    s  = wave_reduce_sum(s);
    s2 = wave_reduce_sum(s2);
    float mu  = s * (1.f / 256.f);
    float var = s2 * (1.f / 256.f) - mu * mu;
    float rs = rsqrtf(var + 1e-5f);
    float4 gv = *(const float4*)(g + lane * 4);
    float4 bv = *(const float4*)(bb + lane * 4);
    ushort4 u;
    u.x = f2bf(gv.x * (x.x - mu) * rs + bv.x);
    u.y = f2bf(gv.y * (x.y - mu) * rs + bv.y);
    u.z = f2bf(gv.z * (x.z - mu) * rs + bv.z);
    u.w = f2bf(gv.w * (x.w - mu) * rs + bv.w);
    *(ushort4*)(xm + (size_t)row * 512 + 256 + lane * 4) = u;
}

// ---------------- LN2: x += ln(buf); xm[:,0:256] = bf16(x) ----------------
__global__ __launch_bounds__(256) void ln2_kernel(
    const float* __restrict__ buf, const float* __restrict__ g, const float* __restrict__ bb,
    float* __restrict__ x, unsigned short* __restrict__ xm)
{
    int row = (int)((blockIdx.x * (size_t)blockDim.x + threadIdx.x) >> 6);
    int lane = threadIdx.x & 63;
    if (row >= M_TOK) return;
    float4 h = *(const float4*)(buf + (size_t)row * DM + lane * 4);
    float s  = h.x + h.y + h.z + h.w;
    float s2 = h.x*h.x + h.y*h.y + h.z*h.z + h.w*h.w;
    s  = wave_reduce_sum(s);
    s2 = wave_reduce_sum(s2);
    float mu  = s * (1.f / 256.f);
    float var = s2 * (1.f / 256.f) - mu * mu;
    float rs = rsqrtf(var + 1e-5f);
    float4 gv = *(const float4*)(g + lane * 4);
    float4 bv = *(const float4*)(bb + lane * 4);
    float4 xv = *(const float4*)(x + (size_t)row * DM + lane * 4);
    xv.x += gv.x * (h.x - mu) * rs + bv.x;
    xv.y += gv.y * (h.y - mu) * rs + bv.y;
    xv.z += gv.z * (h.z - mu) * rs + bv.z;
    xv.w += gv.w * (h.w - mu) * rs + bv.w;
    *(float4*)(x + (size_t)row * DM + lane * 4) = xv;
    ushort4 u; u.x = f2bf(xv.x); u.y = f2bf(xv.y); u.z = f2bf(xv.z); u.w = f2bf(xv.w);
    *(ushort4*)(xm + (size_t)row * 512 + lane * 4) = u;
}

extern "C" void kernel_launch(void* const* d_in, const int* in_sizes, int n_in,
                              void* d_out, int out_size, void* d_ws, size_t ws_size,
                              hipStream_t stream)
{
    const float* feat = (const float*)d_in[1];
    const float* fc   = (const float*)d_in[2];
    const float* Wq   = (const float*)d_in[3];
    const float* Wk   = (const float*)d_in[4];
    const float* Wv   = (const float*)d_in[5];
    const float* Wm   = (const float*)d_in[6];
    const float* W1   = (const float*)d_in[7];
    const float* W2   = (const float*)d_in[8];
    const float* g1   = (const float*)d_in[9];
    const float* b1   = (const float*)d_in[10];
    const float* g2   = (const float*)d_in[11];
    const float* b2   = (const float*)d_in[12];
    float* x = (float*)d_out;

    char* ws = (char*)d_ws;
    auto alloc = [&](size_t bytes) { char* p = ws; ws += (bytes + 255) & ~(size_t)255; return p; };
    int*   seg   = (int*)  alloc((size_t)M_TOK * 4);
    float* KV    = (float*)alloc((size_t)BATCH * KCLS * NHEAD * HD * HD * 4);
    float* Ks    = (float*)alloc((size_t)BATCH * KCLS * NHEAD * HD * 4);
    float* part  = (float*)alloc((size_t)BATCH * NHEAD * KVSEG * PART_STRIDE * 4);
    unsigned short* xm = (unsigned short*)alloc((size_t)M_TOK * 512 * 2);
    char* bufA = alloc((size_t)M_TOK * 512 * 2);   // Q fp32 [M][256] then h bf16 [M][512]
    char* bufB = alloc((size_t)M_TOK * 256 * 4);   // K fp32, then GEMM fp32 outs
    char* bufC = alloc((size_t)M_TOK * 256 * 4);   // V fp32, then msgb bf16
    unsigned short* WqkvT = (unsigned short*)alloc((size_t)NL * 768 * 256 * 2);
    unsigned short* WmT   = (unsigned short*)alloc((size_t)NL * 256 * 256 * 2);
    unsigned short* W1T   = (unsigned short*)alloc((size_t)NL * 512 * 512 * 2);
    unsigned short* W2T   = (unsigned short*)alloc((size_t)NL * 256 * 512 * 2);

    float* Qb = (float*)bufA;
    unsigned short* hb = (unsigned short*)bufA;
    float* Kb = (float*)bufB;
    float* tmp = (float*)bufB;
    float* Vb = (float*)bufC;
    unsigned short* msgb = (unsigned short*)bufC;

    // weight transpose+convert (per launch; small)
    for (int li = 0; li < NL; ++li) {
        transpose_bf16<<<dim3(4, 4), 256, 0, stream>>>(Wq + (size_t)li*65536, WqkvT + (size_t)li*768*256, 256, 256);
        transpose_bf16<<<dim3(4, 4), 256, 0, stream>>>(Wk + (size_t)li*65536, WqkvT + (size_t)li*768*256 + 65536, 256, 256);
        transpose_bf16<<<dim3(4, 4), 256, 0, stream>>>(Wv + (size_t)li*65536, WqkvT + (size_t)li*768*256 + 131072, 256, 256);
        transpose_bf16<<<dim3(4, 4), 256, 0, stream>>>(Wm + (size_t)li*65536, WmT + (size_t)li*65536, 256, 256);
        transpose_bf16<<<dim3(8, 8), 256, 0, stream>>>(W1 + (size_t)li*262144, W1T + (size_t)li*262144, 512, 512);
        transpose_bf16<<<dim3(8, 4), 256, 0, stream>>>(W2 + (size_t)li*131072, W2T + (size_t)li*131072, 512, 256);
    }

    init_kernel<<<8192, 256, 0, stream>>>(feat, x, xm);
    route_kernel<<<8192, 256, 0, stream>>>(feat, fc, seg);

    for (int li = 0; li < NL; ++li) {
        const unsigned short* wqkv = WqkvT + (size_t)li * 768 * 256;
        const unsigned short* wm   = WmT + (size_t)li * 65536;
        const unsigned short* w1   = W1T + (size_t)li * 262144;
        const unsigned short* w2   = W2T + (size_t)li * 131072;

        // Q,K (elu+1) and V : one fused GEMM, N=768
        mfma_gemm<256, 512, 1><<<dim3(256, 6), 256, 0, stream>>>(xm, wqkv, Qb, Kb, Vb, nullptr);

        // KV/Ksum: per-segment partials, then tree reduce (no atomics)
        kv_kernel<<<BATCH * NHEAD * KVSEG, 256, 0, stream>>>(Kb, Vb, seg, part);
        kv_reduce<<<BATCH * NHEAD * KCLS, 256, 0, stream>>>(part, KV, Ks);

        // msgb (bf16) <- attention message
        msg_kernel<<<M_TOK, 256, 0, stream>>>(Qb, KV, Ks, seg, msgb);

        // tmp <- msg @ Wm ; xm[:,256:512] <- bf16(LN1(tmp))
        mfma_gemm<256, 256, 0><<<dim3(256, 2), 256, 0, stream>>>(msgb, wm, tmp, nullptr, nullptr, nullptr);
        ln1_kernel<<<8192, 256, 0, stream>>>(tmp, g1 + li * DM, b1 + li * DM, xm);

        // hb (bf16 [M][512]) <- relu(concat(x,m1) @ W1)
        mfma_gemm<512, 512, 2><<<dim3(256, 4), 256, 0, stream>>>(xm, w1, nullptr, nullptr, nullptr, hb);

        // tmp <- h @ W2 ; x += LN2(tmp); xm[:,0:256] <- bf16(x)
        mfma_gemm<512, 512, 0><<<dim3(256, 2), 256, 0, stream>>>(hb, w2, tmp, nullptr, nullptr, nullptr);
        ln2_kernel<<<8192, 256, 0, stream>>>(tmp, g2 + li * DM, b2 + li * DM, x, xm);
    }
}

// Round 4
// 1164.410 us; speedup vs baseline: 3.2558x; 1.4438x over previous
//
#include <hip/hip_runtime.h>
#include <hip/hip_bf16.h>
#include <math.h>

#define DM 256
#define NHEAD 8
#define HD 32
#define NL 4
#define BATCH 8
#define SEQ 4096
#define KCLS 10
#define M_TOK (BATCH*SEQ)   // 32768

#define BM 128
#define BN 128
#define BKG 64

#define KVSEG 16
#define KVUNROLL 8
#define PART_STRIDE (KCLS * 1056)   // per-block partial: 10 clusters x (1024 KV + 32 Ks)

using bf16x8 = __attribute__((ext_vector_type(8))) short;
using f32x4  = __attribute__((ext_vector_type(4))) float;

__device__ __forceinline__ unsigned short f2bf(float f) {
    __hip_bfloat16 b = __float2bfloat16(f);
    return __builtin_bit_cast(unsigned short, b);
}
__device__ __forceinline__ float bf2f(unsigned short u) {
    unsigned v = (unsigned)u << 16;
    return __builtin_bit_cast(float, v);
}

__device__ __forceinline__ float wave_reduce_sum(float v) {
    #pragma unroll
    for (int off = 32; off > 0; off >>= 1) v += __shfl_xor(v, off, 64);
    return v;
}

// ---------------- init: x = feat (fp32), xm[:,0:256] = bf16(feat) ----------------
__global__ __launch_bounds__(256) void init_kernel(const float* __restrict__ feat,
                                                   float* __restrict__ x,
                                                   unsigned short* __restrict__ xm) {
    int i = blockIdx.x * 256 + threadIdx.x;      // over M_TOK*64 quads
    int row = i >> 6, c4 = (i & 63) * 4;
    float4 v = *(const float4*)(feat + (size_t)row * DM + c4);
    *(float4*)(x + (size_t)row * DM + c4) = v;
    ushort4 u; u.x = f2bf(v.x); u.y = f2bf(v.y); u.z = f2bf(v.z); u.w = f2bf(v.w);
    *(ushort4*)(xm + (size_t)row * 512 + c4) = u;
}

// ---------------- routing ----------------
__global__ void route_kernel(const float* __restrict__ x, const float* __restrict__ fc,
                             int* __restrict__ seg) {
    int wid = (int)((blockIdx.x * (size_t)blockDim.x + threadIdx.x) >> 6);
    int lane = threadIdx.x & 63;
    if (wid >= M_TOK) return;
    int b = wid / SEQ;
    float4 xv = *(const float4*)(x + (size_t)wid * DM + lane * 4);
    float nb2 = xv.x*xv.x + xv.y*xv.y + xv.z*xv.z + xv.w*xv.w;
    nb2 = wave_reduce_sum(nb2);
    float nb = sqrtf(nb2);
    float best = -1e30f; int bestk = 0;
    for (int k = 0; k < KCLS; ++k) {
        float4 fv = *(const float4*)(fc + ((size_t)(b * KCLS + k)) * DM + lane * 4);
        float d = fv.x*xv.x + fv.y*xv.y + fv.z*xv.z + fv.w*xv.w;
        float n = fv.x*fv.x + fv.y*fv.y + fv.z*fv.z + fv.w*fv.w;
        d = wave_reduce_sum(d);
        n = wave_reduce_sum(n);
        float sim = d / fmaxf(sqrtf(n) * nb, 1e-8f);
        if (sim > best) { best = sim; bestk = k; }
    }
    if (lane == 0) seg[wid] = bestk;
}

// ---------------- weight transpose+convert: src [K][N] fp32 -> dst [N][K] bf16 ----------------
__global__ __launch_bounds__(256) void transpose_bf16(const float* __restrict__ src,
                                                      unsigned short* __restrict__ dst,
                                                      int K, int N) {
    __shared__ float s[64][65];
    int k0 = blockIdx.x * 64, n0 = blockIdx.y * 64;
    int t = threadIdx.x;
    int r = t >> 4, c4 = (t & 15) * 4;
    #pragma unroll
    for (int i = 0; i < 4; ++i) {
        float4 v = *(const float4*)(src + (size_t)(k0 + r + i*16) * N + n0 + c4);
        s[c4+0][r+i*16] = v.x; s[c4+1][r+i*16] = v.y;
        s[c4+2][r+i*16] = v.z; s[c4+3][r+i*16] = v.w;
    }
    __syncthreads();
    #pragma unroll
    for (int i = 0; i < 4; ++i) {
        int nr = r + i*16;
        ushort4 u;
        u.x = f2bf(s[nr][c4+0]); u.y = f2bf(s[nr][c4+1]);
        u.z = f2bf(s[nr][c4+2]); u.w = f2bf(s[nr][c4+3]);
        *(ushort4*)(dst + (size_t)(n0 + nr) * K + k0 + c4) = u;
    }
}

// ---------------- bf16 MFMA GEMM: out = act( A[M,KD] * Bt[N,KD]^T ) ----------------
// MODE 0: fp32 out Of [M][256] (N=256), no act
// MODE 1: QKV (N=768): bf16 outs: cols 0-255 -> Ob0 (elu+1), 256-511 -> Ob1 (elu+1), 512-767 -> Ob2
// MODE 2: W1 (N=512): bf16 out Ob0 [M][512], relu
template<int KD, int AS, int MODE>
__global__ __launch_bounds__(256) void mfma_gemm(
    const unsigned short* __restrict__ A, const unsigned short* __restrict__ Bt,
    float* __restrict__ Of,
    unsigned short* __restrict__ Ob0, unsigned short* __restrict__ Ob1,
    unsigned short* __restrict__ Ob2)
{
    __shared__ unsigned short As[BM * BKG];
    __shared__ unsigned short Bs[BN * BKG];
    int t = threadIdx.x;
    int lane = t & 63;
    int w = t >> 6;
    int wm = w & 1, wn = w >> 1;         // 2x2 wave grid, each wave 64x64
    int bm = blockIdx.x * BM;
    int bn = blockIdx.y * BN;

    f32x4 acc[4][4];
    #pragma unroll
    for (int m = 0; m < 4; ++m)
        #pragma unroll
        for (int n = 0; n < 4; ++n)
            acc[m][n] = (f32x4){0.f, 0.f, 0.f, 0.f};

    for (int k0 = 0; k0 < KD; k0 += BKG) {
        #pragma unroll
        for (int i = 0; i < 4; ++i) {
            int chunk = i * 256 + t;
            int row = chunk >> 3, cc = chunk & 7;
            __builtin_amdgcn_global_load_lds(
                (const __attribute__((address_space(1))) void*)(A + (size_t)(bm + row) * AS + k0 + cc * 8),
                (__attribute__((address_space(3))) void*)((char*)As + chunk * 16), 16, 0, 0);
            __builtin_amdgcn_global_load_lds(
                (const __attribute__((address_space(1))) void*)(Bt + (size_t)(bn + row) * KD + k0 + cc * 8),
                (__attribute__((address_space(3))) void*)((char*)Bs + chunk * 16), 16, 0, 0);
        }
        asm volatile("s_waitcnt vmcnt(0)");
        __syncthreads();
        #pragma unroll
        for (int kk = 0; kk < 2; ++kk) {
            int kbyte = (kk * 32 + (lane >> 4) * 8) * 2;
            bf16x8 af[4], bfr[4];
            #pragma unroll
            for (int m = 0; m < 4; ++m)
                af[m] = *(const bf16x8*)((const char*)As + (wm*64 + m*16 + (lane & 15)) * 128 + kbyte);
            #pragma unroll
            for (int n = 0; n < 4; ++n)
                bfr[n] = *(const bf16x8*)((const char*)Bs + (wn*64 + n*16 + (lane & 15)) * 128 + kbyte);
            #pragma unroll
            for (int m = 0; m < 4; ++m)
                #pragma unroll
                for (int n = 0; n < 4; ++n)
                    acc[m][n] = __builtin_amdgcn_mfma_f32_16x16x32_bf16(af[m], bfr[n], acc[m][n], 0, 0, 0);
        }
        __syncthreads();
    }

    int row0 = bm + wm * 64 + (lane >> 4) * 4;
    int lcol = wn * 64 + (lane & 15);
    if (MODE == 0) {
        #pragma unroll
        for (int m = 0; m < 4; ++m)
            #pragma unroll
            for (int n = 0; n < 4; ++n)
                #pragma unroll
                for (int j = 0; j < 4; ++j)
                    Of[(size_t)(row0 + m*16 + j) * 256 + bn + lcol + n*16] = acc[m][n][j];
    } else if (MODE == 1) {
        unsigned short* Obuf = (bn < 256) ? Ob0 : (bn < 512) ? Ob1 : Ob2;
        const bool act = (bn < 512);
        int cc0 = (bn & 255) + lcol;
        #pragma unroll
        for (int m = 0; m < 4; ++m)
            #pragma unroll
            for (int n = 0; n < 4; ++n)
                #pragma unroll
                for (int j = 0; j < 4; ++j) {
                    float v = acc[m][n][j];
                    if (act) v = (v > 0.f) ? v + 1.f : expf(v);
                    Obuf[(size_t)(row0 + m*16 + j) * 256 + cc0 + n*16] = f2bf(v);
                }
    } else {
        #pragma unroll
        for (int m = 0; m < 4; ++m)
            #pragma unroll
            for (int n = 0; n < 4; ++n)
                #pragma unroll
                for (int j = 0; j < 4; ++j)
                    Ob0[(size_t)(row0 + m*16 + j) * 512 + bn + lcol + n*16] =
                        f2bf(fmaxf(acc[m][n][j], 0.f));
    }
}

// ---------------- KV / Ksum segment partials (bf16 in, unroll-8 prefetch, no atomics) ----------------
__global__ __launch_bounds__(256) void kv_kernel(
    const unsigned short* __restrict__ Kf, const unsigned short* __restrict__ V,
    const int* __restrict__ seg, float* __restrict__ part)
{
    int blk = blockIdx.x;
    int s = blk & (KVSEG - 1);
    int bh = blk / KVSEG;
    int b = bh >> 3, h = bh & 7;
    int t = threadIdx.x;
    int d = t >> 3, e0 = (t & 7) * 4;
    float4 a0 = {0,0,0,0}, a1 = a0, a2 = a0, a3 = a0, a4 = a0;
    float4 a5 = a0, a6 = a0, a7 = a0, a8 = a0, a9 = a0;
    float ks0 = 0, ks1 = 0, ks2 = 0, ks3 = 0, ks4 = 0;
    float ks5 = 0, ks6 = 0, ks7 = 0, ks8 = 0, ks9 = 0;
    const int lbeg = s * (SEQ / KVSEG);                 // 256 tokens per block
    const unsigned short* Kp = Kf + (size_t)(b * SEQ + lbeg) * DM + h * HD + d;
    const unsigned short* Vp = V  + (size_t)(b * SEQ + lbeg) * DM + h * HD + e0;
    const int* segp = seg + b * SEQ + lbeg;
    for (int l0 = 0; l0 < SEQ / KVSEG; l0 += KVUNROLL) {
        int cc[KVUNROLL];
        unsigned short ku[KVUNROLL];
        ushort4 vu[KVUNROLL];
        #pragma unroll
        for (int u = 0; u < KVUNROLL; ++u)
            cc[u] = segp[l0 + u];
        #pragma unroll
        for (int u = 0; u < KVUNROLL; ++u) {
            ku[u] = Kp[(size_t)(l0 + u) * DM];
            vu[u] = *(const ushort4*)(Vp + (size_t)(l0 + u) * DM);
        }
        #pragma unroll
        for (int u = 0; u < KVUNROLL; ++u) {
            float kd = bf2f(ku[u]);
            float4 v4;
            v4.x = bf2f(vu[u].x); v4.y = bf2f(vu[u].y);
            v4.z = bf2f(vu[u].z); v4.w = bf2f(vu[u].w);
            int cs = __builtin_amdgcn_readfirstlane(cc[u]);
            switch (cs) {
            #define ACC_CASE(n) case n: \
                a##n.x = fmaf(kd, v4.x, a##n.x); a##n.y = fmaf(kd, v4.y, a##n.y); \
                a##n.z = fmaf(kd, v4.z, a##n.z); a##n.w = fmaf(kd, v4.w, a##n.w); \
                ks##n += kd; break;
            ACC_CASE(0) ACC_CASE(1) ACC_CASE(2) ACC_CASE(3) ACC_CASE(4)
            ACC_CASE(5) ACC_CASE(6) ACC_CASE(7) ACC_CASE(8) ACC_CASE(9)
            #undef ACC_CASE
            }
        }
    }
    float* pb = part + (size_t)blk * PART_STRIDE;
    #define WRITE_C(n) { \
        *(float4*)(pb + n * 1056 + d * 32 + e0) = a##n; \
        if ((t & 7) == 0) pb[n * 1056 + 1024 + d] = ks##n; }
    WRITE_C(0) WRITE_C(1) WRITE_C(2) WRITE_C(3) WRITE_C(4)
    WRITE_C(5) WRITE_C(6) WRITE_C(7) WRITE_C(8) WRITE_C(9)
    #undef WRITE_C
}

// ---------------- reduce partials -> KV, Ks ----------------
__global__ __launch_bounds__(256) void kv_reduce(
    const float* __restrict__ part, float* __restrict__ KV, float* __restrict__ Ks)
{
    int blk = blockIdx.x;          // bh * KCLS + c
    int c = blk % KCLS;
    int bh = blk / KCLS;
    int b = bh >> 3, h = bh & 7;
    int t = threadIdx.x;
    const float* pb = part + (size_t)bh * KVSEG * PART_STRIDE + c * 1056;
    float4 acc = {0, 0, 0, 0};
    float ka = 0.f;
    #pragma unroll
    for (int s = 0; s < KVSEG; ++s) {
        float4 v = *(const float4*)(pb + (size_t)s * PART_STRIDE + t * 4);
        acc.x += v.x; acc.y += v.y; acc.z += v.z; acc.w += v.w;
        if (t < 32) ka += pb[(size_t)s * PART_STRIDE + 1024 + t];
    }
    *(float4*)(KV + ((size_t)(b * KCLS + c) * NHEAD + h) * HD * HD + t * 4) = acc;
    if (t < 32) Ks[((size_t)(b * KCLS + c) * NHEAD + h) * HD + t] = ka;
}

// ---------------- per-token message (bf16 Q in) -> bf16 ----------------
__global__ __launch_bounds__(256) void msg_kernel(
    const unsigned short* __restrict__ Q, const float* __restrict__ KV,
    const float* __restrict__ Ks, const int* __restrict__ seg,
    unsigned short* __restrict__ msgb)
{
    int tokn = blockIdx.x;
    int b = tokn / SEQ;
    int t = threadIdx.x;
    int h = t >> 5, e = t & 31;
    __shared__ float sQ[DM];
    sQ[t] = bf2f(Q[(size_t)tokn * DM + t]);
    __syncthreads();
    int c = seg[tokn];
    const float* kvp = KV + ((size_t)(b * KCLS + c) * NHEAD + h) * HD * HD;
    const float* ksp = Ks + ((size_t)(b * KCLS + c) * NHEAD + h) * HD;
    float macc = 0.f, zacc = 0.f;
    #pragma unroll
    for (int dd = 0; dd < 32; ++dd) {
        float qd = sQ[h * 32 + dd];
        macc = fmaf(qd, kvp[dd * 32 + e], macc);
        zacc = fmaf(qd, ksp[dd], zacc);
    }
    msgb[(size_t)tokn * DM + t] = f2bf(macc / (zacc + 1e-6f));
}

// ---------------- LN1: bf16 out into xm[:,256:512] ----------------
__global__ __launch_bounds__(256) void ln1_kernel(
    const float* __restrict__ buf, const float* __restrict__ g, const float* __restrict__ bb,
    unsigned short* __restrict__ xm)
{
    int row = (int)((blockIdx.x * (size_t)blockDim.x + threadIdx.x) >> 6);
    int lane = threadIdx.x & 63;
    if (row >= M_TOK) return;
    float4 x = *(const float4*)(buf + (size_t)row * DM + lane * 4);
    float s  = x.x + x.y + x.z + x.w;
    float s2 = x.x*x.x + x.y*x.y + x.z*x.z + x.w*x.w;
    s  = wave_reduce_sum(s);
    s2 = wave_reduce_sum(s2);
    float mu  = s * (1.f / 256.f);
    float var = s2 * (1.f / 256.f) - mu * mu;
    float rs = rsqrtf(var + 1e-5f);
    float4 gv = *(const float4*)(g + lane * 4);
    float4 bv = *(const float4*)(bb + lane * 4);
    ushort4 u;
    u.x = f2bf(gv.x * (x.x - mu) * rs + bv.x);
    u.y = f2bf(gv.y * (x.y - mu) * rs + bv.y);
    u.z = f2bf(gv.z * (x.z - mu) * rs + bv.z);
    u.w = f2bf(gv.w * (x.w - mu) * rs + bv.w);
    *(ushort4*)(xm + (size_t)row * 512 + 256 + lane * 4) = u;
}

// ---------------- LN2: x += ln(buf); xm[:,0:256] = bf16(x) ----------------
__global__ __launch_bounds__(256) void ln2_kernel(
    const float* __restrict__ buf, const float* __restrict__ g, const float* __restrict__ bb,
    float* __restrict__ x, unsigned short* __restrict__ xm)
{
    int row = (int)((blockIdx.x * (size_t)blockDim.x + threadIdx.x) >> 6);
    int lane = threadIdx.x & 63;
    if (row >= M_TOK) return;
    float4 h = *(const float4*)(buf + (size_t)row * DM + lane * 4);
    float s  = h.x + h.y + h.z + h.w;
    float s2 = h.x*h.x + h.y*h.y + h.z*h.z + h.w*h.w;
    s  = wave_reduce_sum(s);
    s2 = wave_reduce_sum(s2);
    float mu  = s * (1.f / 256.f);
    float var = s2 * (1.f / 256.f) - mu * mu;
    float rs = rsqrtf(var + 1e-5f);
    float4 gv = *(const float4*)(g + lane * 4);
    float4 bv = *(const float4*)(bb + lane * 4);
    float4 xv = *(const float4*)(x + (size_t)row * DM + lane * 4);
    xv.x += gv.x * (h.x - mu) * rs + bv.x;
    xv.y += gv.y * (h.y - mu) * rs + bv.y;
    xv.z += gv.z * (h.z - mu) * rs + bv.z;
    xv.w += gv.w * (h.w - mu) * rs + bv.w;
    *(float4*)(x + (size_t)row * DM + lane * 4) = xv;
    ushort4 u; u.x = f2bf(xv.x); u.y = f2bf(xv.y); u.z = f2bf(xv.z); u.w = f2bf(xv.w);
    *(ushort4*)(xm + (size_t)row * 512 + lane * 4) = u;
}

extern "C" void kernel_launch(void* const* d_in, const int* in_sizes, int n_in,
                              void* d_out, int out_size, void* d_ws, size_t ws_size,
                              hipStream_t stream)
{
    const float* feat = (const float*)d_in[1];
    const float* fc   = (const float*)d_in[2];
    const float* Wq   = (const float*)d_in[3];
    const float* Wk   = (const float*)d_in[4];
    const float* Wv   = (const float*)d_in[5];
    const float* Wm   = (const float*)d_in[6];
    const float* W1   = (const float*)d_in[7];
    const float* W2   = (const float*)d_in[8];
    const float* g1   = (const float*)d_in[9];
    const float* b1   = (const float*)d_in[10];
    const float* g2   = (const float*)d_in[11];
    const float* b2   = (const float*)d_in[12];
    float* x = (float*)d_out;

    char* ws = (char*)d_ws;
    auto alloc = [&](size_t bytes) { char* p = ws; ws += (bytes + 255) & ~(size_t)255; return p; };
    int*   seg   = (int*)  alloc((size_t)M_TOK * 4);
    float* KV    = (float*)alloc((size_t)BATCH * KCLS * NHEAD * HD * HD * 4);
    float* Ks    = (float*)alloc((size_t)BATCH * KCLS * NHEAD * HD * 4);
    float* part  = (float*)alloc((size_t)BATCH * NHEAD * KVSEG * PART_STRIDE * 4);
    unsigned short* xm = (unsigned short*)alloc((size_t)M_TOK * 512 * 2);
    char* bufA = alloc((size_t)M_TOK * 512 * 2);   // Qb bf16 [M][256] then hb bf16 [M][512]
    char* bufB = alloc((size_t)M_TOK * 256 * 4);   // Kb bf16 / tmp fp32
    char* bufC = alloc((size_t)M_TOK * 256 * 2);   // Vb bf16 then msgb bf16
    unsigned short* WqkvT = (unsigned short*)alloc((size_t)NL * 768 * 256 * 2);
    unsigned short* WmT   = (unsigned short*)alloc((size_t)NL * 256 * 256 * 2);
    unsigned short* W1T   = (unsigned short*)alloc((size_t)NL * 512 * 512 * 2);
    unsigned short* W2T   = (unsigned short*)alloc((size_t)NL * 256 * 512 * 2);

    unsigned short* Qb = (unsigned short*)bufA;
    unsigned short* hb = (unsigned short*)bufA;
    unsigned short* Kb = (unsigned short*)bufB;
    float* tmp = (float*)bufB;
    unsigned short* Vb = (unsigned short*)bufC;
    unsigned short* msgb = (unsigned short*)bufC;

    // weight transpose+convert (per launch; small)
    for (int li = 0; li < NL; ++li) {
        transpose_bf16<<<dim3(4, 4), 256, 0, stream>>>(Wq + (size_t)li*65536, WqkvT + (size_t)li*768*256, 256, 256);
        transpose_bf16<<<dim3(4, 4), 256, 0, stream>>>(Wk + (size_t)li*65536, WqkvT + (size_t)li*768*256 + 65536, 256, 256);
        transpose_bf16<<<dim3(4, 4), 256, 0, stream>>>(Wv + (size_t)li*65536, WqkvT + (size_t)li*768*256 + 131072, 256, 256);
        transpose_bf16<<<dim3(4, 4), 256, 0, stream>>>(Wm + (size_t)li*65536, WmT + (size_t)li*65536, 256, 256);
        transpose_bf16<<<dim3(8, 8), 256, 0, stream>>>(W1 + (size_t)li*262144, W1T + (size_t)li*262144, 512, 512);
        transpose_bf16<<<dim3(8, 4), 256, 0, stream>>>(W2 + (size_t)li*131072, W2T + (size_t)li*131072, 512, 256);
    }

    init_kernel<<<8192, 256, 0, stream>>>(feat, x, xm);
    route_kernel<<<8192, 256, 0, stream>>>(feat, fc, seg);

    for (int li = 0; li < NL; ++li) {
        const unsigned short* wqkv = WqkvT + (size_t)li * 768 * 256;
        const unsigned short* wm   = WmT + (size_t)li * 65536;
        const unsigned short* w1   = W1T + (size_t)li * 262144;
        const unsigned short* w2   = W2T + (size_t)li * 131072;

        // Q,K (elu+1) and V : one fused GEMM, N=768, bf16 outs
        mfma_gemm<256, 512, 1><<<dim3(256, 6), 256, 0, stream>>>(xm, wqkv, nullptr, Qb, Kb, Vb);

        // KV/Ksum: per-segment partials, then tree reduce (no atomics)
        kv_kernel<<<BATCH * NHEAD * KVSEG, 256, 0, stream>>>(Kb, Vb, seg, part);
        kv_reduce<<<BATCH * NHEAD * KCLS, 256, 0, stream>>>(part, KV, Ks);

        // msgb (bf16) <- attention message
        msg_kernel<<<M_TOK, 256, 0, stream>>>(Qb, KV, Ks, seg, msgb);

        // tmp <- msg @ Wm ; xm[:,256:512] <- bf16(LN1(tmp))
        mfma_gemm<256, 256, 0><<<dim3(256, 2), 256, 0, stream>>>(msgb, wm, tmp, nullptr, nullptr, nullptr);
        ln1_kernel<<<8192, 256, 0, stream>>>(tmp, g1 + li * DM, b1 + li * DM, xm);

        // hb (bf16 [M][512]) <- relu(concat(x,m1) @ W1)
        mfma_gemm<512, 512, 2><<<dim3(256, 4), 256, 0, stream>>>(xm, w1, nullptr, hb, nullptr, nullptr);

        // tmp <- h @ W2 ; x += LN2(tmp); xm[:,0:256] <- bf16(x)
        mfma_gemm<512, 512, 0><<<dim3(256, 2), 256, 0, stream>>>(hb, w2, tmp, nullptr, nullptr, nullptr);
        ln2_kernel<<<8192, 256, 0, stream>>>(tmp, g2 + li * DM, b2 + li * DM, x, xm);
    }
}

// Round 5
// 1132.888 us; speedup vs baseline: 3.3464x; 1.0278x over previous
//
#include <hip/hip_runtime.h>
#include <hip/hip_bf16.h>
#include <math.h>

#define DM 256
#define NHEAD 8
#define HD 32
#define NL 4
#define BATCH 8
#define SEQ 4096
#define KCLS 10
#define M_TOK (BATCH*SEQ)   // 32768

#define BM 128
#define BN 128
#define BKG 64

#define KVSEG 16
#define KVUNROLL 8
#define PART_STRIDE (KCLS * 1056)   // per-block partial: 10 clusters x (1024 KV + 32 Ks)

using bf16x8 = __attribute__((ext_vector_type(8))) short;
using f32x4  = __attribute__((ext_vector_type(4))) float;

__device__ __forceinline__ unsigned short f2bf(float f) {
    __hip_bfloat16 b = __float2bfloat16(f);
    return __builtin_bit_cast(unsigned short, b);
}
__device__ __forceinline__ float bf2f(unsigned short u) {
    unsigned v = (unsigned)u << 16;
    return __builtin_bit_cast(float, v);
}

__device__ __forceinline__ float wave_reduce_sum(float v) {
    #pragma unroll
    for (int off = 32; off > 0; off >>= 1) v += __shfl_xor(v, off, 64);
    return v;
}

// ---------------- init: x = feat (fp32), xm[:,0:256] = bf16(feat) ----------------
__global__ __launch_bounds__(256) void init_kernel(const float* __restrict__ feat,
                                                   float* __restrict__ x,
                                                   unsigned short* __restrict__ xm) {
    int i = blockIdx.x * 256 + threadIdx.x;      // over M_TOK*64 quads
    int row = i >> 6, c4 = (i & 63) * 4;
    float4 v = *(const float4*)(feat + (size_t)row * DM + c4);
    *(float4*)(x + (size_t)row * DM + c4) = v;
    ushort4 u; u.x = f2bf(v.x); u.y = f2bf(v.y); u.z = f2bf(v.z); u.w = f2bf(v.w);
    *(ushort4*)(xm + (size_t)row * 512 + c4) = u;
}

// ---------------- routing ----------------
__global__ void route_kernel(const float* __restrict__ x, const float* __restrict__ fc,
                             int* __restrict__ seg) {
    int wid = (int)((blockIdx.x * (size_t)blockDim.x + threadIdx.x) >> 6);
    int lane = threadIdx.x & 63;
    if (wid >= M_TOK) return;
    int b = wid / SEQ;
    float4 xv = *(const float4*)(x + (size_t)wid * DM + lane * 4);
    float nb2 = xv.x*xv.x + xv.y*xv.y + xv.z*xv.z + xv.w*xv.w;
    nb2 = wave_reduce_sum(nb2);
    float nb = sqrtf(nb2);
    float best = -1e30f; int bestk = 0;
    for (int k = 0; k < KCLS; ++k) {
        float4 fv = *(const float4*)(fc + ((size_t)(b * KCLS + k)) * DM + lane * 4);
        float d = fv.x*xv.x + fv.y*xv.y + fv.z*xv.z + fv.w*xv.w;
        float n = fv.x*fv.x + fv.y*fv.y + fv.z*fv.z + fv.w*fv.w;
        d = wave_reduce_sum(d);
        n = wave_reduce_sum(n);
        float sim = d / fmaxf(sqrtf(n) * nb, 1e-8f);
        if (sim > best) { best = sim; bestk = k; }
    }
    if (lane == 0) seg[wid] = bestk;
}

// ---------------- weight transpose+convert: src [K][N] fp32 -> dst [N][K] bf16 ----------------
__global__ __launch_bounds__(256) void transpose_bf16(const float* __restrict__ src,
                                                      unsigned short* __restrict__ dst,
                                                      int K, int N) {
    __shared__ float s[64][65];
    int k0 = blockIdx.x * 64, n0 = blockIdx.y * 64;
    int t = threadIdx.x;
    int r = t >> 4, c4 = (t & 15) * 4;
    #pragma unroll
    for (int i = 0; i < 4; ++i) {
        float4 v = *(const float4*)(src + (size_t)(k0 + r + i*16) * N + n0 + c4);
        s[c4+0][r+i*16] = v.x; s[c4+1][r+i*16] = v.y;
        s[c4+2][r+i*16] = v.z; s[c4+3][r+i*16] = v.w;
    }
    __syncthreads();
    #pragma unroll
    for (int i = 0; i < 4; ++i) {
        int nr = r + i*16;
        ushort4 u;
        u.x = f2bf(s[nr][c4+0]); u.y = f2bf(s[nr][c4+1]);
        u.z = f2bf(s[nr][c4+2]); u.w = f2bf(s[nr][c4+3]);
        *(ushort4*)(dst + (size_t)(n0 + nr) * K + k0 + c4) = u;
    }
}

// ---------------- bf16 MFMA GEMM (128x128 tile): out = act( A[M,KD] * Bt[N,KD]^T ) ----------------
// MODE 1: QKV (N=768): bf16 outs: cols 0-255 -> Ob0 (elu+1), 256-511 -> Ob1 (elu+1), 512-767 -> Ob2
// MODE 2: W1 (N=512): bf16 out Ob0 [M][512], relu
template<int KD, int AS, int MODE>
__global__ __launch_bounds__(256) void mfma_gemm(
    const unsigned short* __restrict__ A, const unsigned short* __restrict__ Bt,
    unsigned short* __restrict__ Ob0, unsigned short* __restrict__ Ob1,
    unsigned short* __restrict__ Ob2)
{
    __shared__ unsigned short As[BM * BKG];
    __shared__ unsigned short Bs[BN * BKG];
    int t = threadIdx.x;
    int lane = t & 63;
    int w = t >> 6;
    int wm = w & 1, wn = w >> 1;         // 2x2 wave grid, each wave 64x64
    int bm = blockIdx.x * BM;
    int bn = blockIdx.y * BN;

    f32x4 acc[4][4];
    #pragma unroll
    for (int m = 0; m < 4; ++m)
        #pragma unroll
        for (int n = 0; n < 4; ++n)
            acc[m][n] = (f32x4){0.f, 0.f, 0.f, 0.f};

    for (int k0 = 0; k0 < KD; k0 += BKG) {
        #pragma unroll
        for (int i = 0; i < 4; ++i) {
            int chunk = i * 256 + t;
            int row = chunk >> 3, cc = chunk & 7;
            __builtin_amdgcn_global_load_lds(
                (const __attribute__((address_space(1))) void*)(A + (size_t)(bm + row) * AS + k0 + cc * 8),
                (__attribute__((address_space(3))) void*)((char*)As + chunk * 16), 16, 0, 0);
            __builtin_amdgcn_global_load_lds(
                (const __attribute__((address_space(1))) void*)(Bt + (size_t)(bn + row) * KD + k0 + cc * 8),
                (__attribute__((address_space(3))) void*)((char*)Bs + chunk * 16), 16, 0, 0);
        }
        asm volatile("s_waitcnt vmcnt(0)");
        __syncthreads();
        #pragma unroll
        for (int kk = 0; kk < 2; ++kk) {
            int kbyte = (kk * 32 + (lane >> 4) * 8) * 2;
            bf16x8 af[4], bfr[4];
            #pragma unroll
            for (int m = 0; m < 4; ++m)
                af[m] = *(const bf16x8*)((const char*)As + (wm*64 + m*16 + (lane & 15)) * 128 + kbyte);
            #pragma unroll
            for (int n = 0; n < 4; ++n)
                bfr[n] = *(const bf16x8*)((const char*)Bs + (wn*64 + n*16 + (lane & 15)) * 128 + kbyte);
            #pragma unroll
            for (int m = 0; m < 4; ++m)
                #pragma unroll
                for (int n = 0; n < 4; ++n)
                    acc[m][n] = __builtin_amdgcn_mfma_f32_16x16x32_bf16(af[m], bfr[n], acc[m][n], 0, 0, 0);
        }
        __syncthreads();
    }

    int row0 = bm + wm * 64 + (lane >> 4) * 4;
    int lcol = wn * 64 + (lane & 15);
    if (MODE == 1) {
        unsigned short* Obuf = (bn < 256) ? Ob0 : (bn < 512) ? Ob1 : Ob2;
        const bool act = (bn < 512);
        int cc0 = (bn & 255) + lcol;
        #pragma unroll
        for (int m = 0; m < 4; ++m)
            #pragma unroll
            for (int n = 0; n < 4; ++n)
                #pragma unroll
                for (int j = 0; j < 4; ++j) {
                    float v = acc[m][n][j];
                    if (act) v = (v > 0.f) ? v + 1.f : expf(v);
                    Obuf[(size_t)(row0 + m*16 + j) * 256 + cc0 + n*16] = f2bf(v);
                }
    } else {
        #pragma unroll
        for (int m = 0; m < 4; ++m)
            #pragma unroll
            for (int n = 0; n < 4; ++n)
                #pragma unroll
                for (int j = 0; j < 4; ++j)
                    Ob0[(size_t)(row0 + m*16 + j) * 512 + bn + lcol + n*16] =
                        f2bf(fmaxf(acc[m][n][j], 0.f));
    }
}

// ---------------- fused GEMM + LayerNorm (full rows per block: BM=64, BN=256) ----------------
// LNMODE 1: xm[:,256:512] = bf16( LN(A@Bt^T, g, b) )
// LNMODE 2: x += LN(A@Bt^T, g, b); xm[:,0:256] = bf16(x)
template<int KD, int LNMODE>
__global__ __launch_bounds__(256) void gemm_ln(
    const unsigned short* __restrict__ A, const unsigned short* __restrict__ Bt,
    const float* __restrict__ g, const float* __restrict__ bb,
    float* __restrict__ x, unsigned short* __restrict__ xm)
{
    __shared__ unsigned short As[64 * BKG];
    __shared__ unsigned short Bs[256 * BKG];
    __shared__ float redS[4][64];
    __shared__ float redQ[4][64];
    int t = threadIdx.x;
    int lane = t & 63;
    int w = t >> 6;                      // wave covers cols [w*64, w*64+64)
    int li = lane & 15, lg = lane >> 4;
    int bm = blockIdx.x * 64;

    f32x4 acc[4][4];
    #pragma unroll
    for (int m = 0; m < 4; ++m)
        #pragma unroll
        for (int n = 0; n < 4; ++n)
            acc[m][n] = (f32x4){0.f, 0.f, 0.f, 0.f};

    for (int k0 = 0; k0 < KD; k0 += BKG) {
        #pragma unroll
        for (int i = 0; i < 2; ++i) {
            int chunk = i * 256 + t;
            int row = chunk >> 3, cc = chunk & 7;
            __builtin_amdgcn_global_load_lds(
                (const __attribute__((address_space(1))) void*)(A + (size_t)(bm + row) * KD + k0 + cc * 8),
                (__attribute__((address_space(3))) void*)((char*)As + chunk * 16), 16, 0, 0);
        }
        #pragma unroll
        for (int i = 0; i < 8; ++i) {
            int chunk = i * 256 + t;
            int row = chunk >> 3, cc = chunk & 7;
            __builtin_amdgcn_global_load_lds(
                (const __attribute__((address_space(1))) void*)(Bt + (size_t)row * KD + k0 + cc * 8),
                (__attribute__((address_space(3))) void*)((char*)Bs + chunk * 16), 16, 0, 0);
        }
        asm volatile("s_waitcnt vmcnt(0)");
        __syncthreads();
        #pragma unroll
        for (int kk = 0; kk < 2; ++kk) {
            int kbyte = (kk * 32 + lg * 8) * 2;
            bf16x8 af[4], bfr[4];
            #pragma unroll
            for (int m = 0; m < 4; ++m)
                af[m] = *(const bf16x8*)((const char*)As + (m*16 + li) * 128 + kbyte);
            #pragma unroll
            for (int n = 0; n < 4; ++n)
                bfr[n] = *(const bf16x8*)((const char*)Bs + (w*64 + n*16 + li) * 128 + kbyte);
            #pragma unroll
            for (int m = 0; m < 4; ++m)
                #pragma unroll
                for (int n = 0; n < 4; ++n)
                    acc[m][n] = __builtin_amdgcn_mfma_f32_16x16x32_bf16(af[m], bfr[n], acc[m][n], 0, 0, 0);
        }
        __syncthreads();
    }

    // ---- row-wise LN over 256 cols (4 waves x 64 cols) ----
    // lane holds rows r = m*16 + lg*4 + j, cols w*64 + n*16 + li
    float vs[4][4], vq[4][4];
    #pragma unroll
    for (int m = 0; m < 4; ++m)
        #pragma unroll
        for (int j = 0; j < 4; ++j) {
            float s = 0.f, q = 0.f;
            #pragma unroll
            for (int n = 0; n < 4; ++n) {
                float v = acc[m][n][j];
                s += v; q += v * v;
            }
            #pragma unroll
            for (int msk = 1; msk < 16; msk <<= 1) {
                s += __shfl_xor(s, msk, 64);
                q += __shfl_xor(q, msk, 64);
            }
            vs[m][j] = s; vq[m][j] = q;
        }
    if (li == 0) {
        #pragma unroll
        for (int m = 0; m < 4; ++m)
            #pragma unroll
            for (int j = 0; j < 4; ++j) {
                redS[w][m*16 + lg*4 + j] = vs[m][j];
                redQ[w][m*16 + lg*4 + j] = vq[m][j];
            }
    }
    __syncthreads();

    float gv[4], bv[4];
    #pragma unroll
    for (int n = 0; n < 4; ++n) {
        int col = w*64 + n*16 + li;
        gv[n] = g[col]; bv[n] = bb[col];
    }
    #pragma unroll
    for (int m = 0; m < 4; ++m)
        #pragma unroll
        for (int j = 0; j < 4; ++j) {
            int r = m*16 + lg*4 + j;
            float S = redS[0][r] + redS[1][r] + redS[2][r] + redS[3][r];
            float Q = redQ[0][r] + redQ[1][r] + redQ[2][r] + redQ[3][r];
            float mu = S * (1.f / 256.f);
            float var = Q * (1.f / 256.f) - mu * mu;
            float rs = rsqrtf(var + 1e-5f);
            #pragma unroll
            for (int n = 0; n < 4; ++n) {
                int col = w*64 + n*16 + li;
                float o = gv[n] * (acc[m][n][j] - mu) * rs + bv[n];
                if (LNMODE == 1) {
                    xm[(size_t)(bm + r) * 512 + 256 + col] = f2bf(o);
                } else {
                    size_t idx = (size_t)(bm + r) * 256 + col;
                    float xv = x[idx] + o;
                    x[idx] = xv;
                    xm[(size_t)(bm + r) * 512 + col] = f2bf(xv);
                }
            }
        }
}

// ---------------- KV / Ksum segment partials (512 thr: 2 groups x 128 tokens, LDS merge) ----------------
__global__ __launch_bounds__(512) void kv_kernel(
    const unsigned short* __restrict__ Kf, const unsigned short* __restrict__ V,
    const int* __restrict__ seg, float* __restrict__ part)
{
    __shared__ float mg[KCLS * 1056];
    int blk = blockIdx.x;
    int s = blk & (KVSEG - 1);
    int bh = blk / KVSEG;
    int b = bh >> 3, h = bh & 7;
    int tid = threadIdx.x;
    int tg = tid >> 8, t = tid & 255;
    int d = t >> 3, e0 = (t & 7) * 4;
    float4 a0 = {0,0,0,0}, a1 = a0, a2 = a0, a3 = a0, a4 = a0;
    float4 a5 = a0, a6 = a0, a7 = a0, a8 = a0, a9 = a0;
    float ks0 = 0, ks1 = 0, ks2 = 0, ks3 = 0, ks4 = 0;
    float ks5 = 0, ks6 = 0, ks7 = 0, ks8 = 0, ks9 = 0;
    const int lbeg = s * (SEQ / KVSEG) + tg * 128;       // 128 tokens per group
    const unsigned short* Kp = Kf + (size_t)(b * SEQ + lbeg) * DM + h * HD + d;
    const unsigned short* Vp = V  + (size_t)(b * SEQ + lbeg) * DM + h * HD + e0;
    const int* segp = seg + b * SEQ + lbeg;
    for (int l0 = 0; l0 < 128; l0 += KVUNROLL) {
        int cc[KVUNROLL];
        unsigned short ku[KVUNROLL];
        ushort4 vu[KVUNROLL];
        #pragma unroll
        for (int u = 0; u < KVUNROLL; ++u)
            cc[u] = segp[l0 + u];
        #pragma unroll
        for (int u = 0; u < KVUNROLL; ++u) {
            ku[u] = Kp[(size_t)(l0 + u) * DM];
            vu[u] = *(const ushort4*)(Vp + (size_t)(l0 + u) * DM);
        }
        #pragma unroll
        for (int u = 0; u < KVUNROLL; ++u) {
            float kd = bf2f(ku[u]);
            float4 v4;
            v4.x = bf2f(vu[u].x); v4.y = bf2f(vu[u].y);
            v4.z = bf2f(vu[u].z); v4.w = bf2f(vu[u].w);
            int cs = __builtin_amdgcn_readfirstlane(cc[u]);
            switch (cs) {
            #define ACC_CASE(n) case n: \
                a##n.x = fmaf(kd, v4.x, a##n.x); a##n.y = fmaf(kd, v4.y, a##n.y); \
                a##n.z = fmaf(kd, v4.z, a##n.z); a##n.w = fmaf(kd, v4.w, a##n.w); \
                ks##n += kd; break;
            ACC_CASE(0) ACC_CASE(1) ACC_CASE(2) ACC_CASE(3) ACC_CASE(4)
            ACC_CASE(5) ACC_CASE(6) ACC_CASE(7) ACC_CASE(8) ACC_CASE(9)
            #undef ACC_CASE
            }
        }
    }
    // group 1 dumps to LDS; group 0 merges and writes the partial
    if (tg == 1) {
        #define DUMP_C(n) { \
            *(float4*)(mg + n * 1056 + d * 32 + e0) = a##n; \
            if ((t & 7) == 0) mg[n * 1056 + 1024 + d] = ks##n; }
        DUMP_C(0) DUMP_C(1) DUMP_C(2) DUMP_C(3) DUMP_C(4)
        DUMP_C(5) DUMP_C(6) DUMP_C(7) DUMP_C(8) DUMP_C(9)
        #undef DUMP_C
    }
    __syncthreads();
    if (tg == 0) {
        float* pb = part + (size_t)blk * PART_STRIDE;
        #define WRITE_C(n) { \
            float4 o = *(const float4*)(mg + n * 1056 + d * 32 + e0); \
            o.x += a##n.x; o.y += a##n.y; o.z += a##n.z; o.w += a##n.w; \
            *(float4*)(pb + n * 1056 + d * 32 + e0) = o; \
            if ((t & 7) == 0) pb[n * 1056 + 1024 + d] = ks##n + mg[n * 1056 + 1024 + d]; }
        WRITE_C(0) WRITE_C(1) WRITE_C(2) WRITE_C(3) WRITE_C(4)
        WRITE_C(5) WRITE_C(6) WRITE_C(7) WRITE_C(8) WRITE_C(9)
        #undef WRITE_C
    }
}

// ---------------- reduce partials -> KV, Ks ----------------
__global__ __launch_bounds__(256) void kv_reduce(
    const float* __restrict__ part, float* __restrict__ KV, float* __restrict__ Ks)
{
    int blk = blockIdx.x;          // bh * KCLS + c
    int c = blk % KCLS;
    int bh = blk / KCLS;
    int b = bh >> 3, h = bh & 7;
    int t = threadIdx.x;
    const float* pb = part + (size_t)bh * KVSEG * PART_STRIDE + c * 1056;
    float4 acc = {0, 0, 0, 0};
    float ka = 0.f;
    #pragma unroll
    for (int s = 0; s < KVSEG; ++s) {
        float4 v = *(const float4*)(pb + (size_t)s * PART_STRIDE + t * 4);
        acc.x += v.x; acc.y += v.y; acc.z += v.z; acc.w += v.w;
        if (t < 32) ka += pb[(size_t)s * PART_STRIDE + 1024 + t];
    }
    *(float4*)(KV + ((size_t)(b * KCLS + c) * NHEAD + h) * HD * HD + t * 4) = acc;
    if (t < 32) Ks[((size_t)(b * KCLS + c) * NHEAD + h) * HD + t] = ka;
}

// ---------------- per-token message (bf16 Q in) -> bf16 ----------------
__global__ __launch_bounds__(256) void msg_kernel(
    const unsigned short* __restrict__ Q, const float* __restrict__ KV,
    const float* __restrict__ Ks, const int* __restrict__ seg,
    unsigned short* __restrict__ msgb)
{
    int tokn = blockIdx.x;
    int b = tokn / SEQ;
    int t = threadIdx.x;
    int h = t >> 5, e = t & 31;
    __shared__ float sQ[DM];
    sQ[t] = bf2f(Q[(size_t)tokn * DM + t]);
    __syncthreads();
    int c = seg[tokn];
    const float* kvp = KV + ((size_t)(b * KCLS + c) * NHEAD + h) * HD * HD;
    const float* ksp = Ks + ((size_t)(b * KCLS + c) * NHEAD + h) * HD;
    float macc = 0.f, zacc = 0.f;
    #pragma unroll
    for (int dd = 0; dd < 32; ++dd) {
        float qd = sQ[h * 32 + dd];
        macc = fmaf(qd, kvp[dd * 32 + e], macc);
        zacc = fmaf(qd, ksp[dd], zacc);
    }
    msgb[(size_t)tokn * DM + t] = f2bf(macc / (zacc + 1e-6f));
}

extern "C" void kernel_launch(void* const* d_in, const int* in_sizes, int n_in,
                              void* d_out, int out_size, void* d_ws, size_t ws_size,
                              hipStream_t stream)
{
    const float* feat = (const float*)d_in[1];
    const float* fc   = (const float*)d_in[2];
    const float* Wq   = (const float*)d_in[3];
    const float* Wk   = (const float*)d_in[4];
    const float* Wv   = (const float*)d_in[5];
    const float* Wm   = (const float*)d_in[6];
    const float* W1   = (const float*)d_in[7];
    const float* W2   = (const float*)d_in[8];
    const float* g1   = (const float*)d_in[9];
    const float* b1   = (const float*)d_in[10];
    const float* g2   = (const float*)d_in[11];
    const float* b2   = (const float*)d_in[12];
    float* x = (float*)d_out;

    char* ws = (char*)d_ws;
    auto alloc = [&](size_t bytes) { char* p = ws; ws += (bytes + 255) & ~(size_t)255; return p; };
    int*   seg   = (int*)  alloc((size_t)M_TOK * 4);
    float* KV    = (float*)alloc((size_t)BATCH * KCLS * NHEAD * HD * HD * 4);
    float* Ks    = (float*)alloc((size_t)BATCH * KCLS * NHEAD * HD * 4);
    float* part  = (float*)alloc((size_t)BATCH * NHEAD * KVSEG * PART_STRIDE * 4);
    unsigned short* xm = (unsigned short*)alloc((size_t)M_TOK * 512 * 2);
    char* bufA = alloc((size_t)M_TOK * 512 * 2);   // Qb bf16 [M][256] then hb bf16 [M][512]
    char* bufB = alloc((size_t)M_TOK * 256 * 2);   // Kb bf16
    char* bufC = alloc((size_t)M_TOK * 256 * 2);   // Vb bf16 then msgb bf16
    unsigned short* WqkvT = (unsigned short*)alloc((size_t)NL * 768 * 256 * 2);
    unsigned short* WmT   = (unsigned short*)alloc((size_t)NL * 256 * 256 * 2);
    unsigned short* W1T   = (unsigned short*)alloc((size_t)NL * 512 * 512 * 2);
    unsigned short* W2T   = (unsigned short*)alloc((size_t)NL * 256 * 512 * 2);

    unsigned short* Qb = (unsigned short*)bufA;
    unsigned short* hb = (unsigned short*)bufA;
    unsigned short* Kb = (unsigned short*)bufB;
    unsigned short* Vb = (unsigned short*)bufC;
    unsigned short* msgb = (unsigned short*)bufC;

    // weight transpose+convert (per launch; small)
    for (int li = 0; li < NL; ++li) {
        transpose_bf16<<<dim3(4, 4), 256, 0, stream>>>(Wq + (size_t)li*65536, WqkvT + (size_t)li*768*256, 256, 256);
        transpose_bf16<<<dim3(4, 4), 256, 0, stream>>>(Wk + (size_t)li*65536, WqkvT + (size_t)li*768*256 + 65536, 256, 256);
        transpose_bf16<<<dim3(4, 4), 256, 0, stream>>>(Wv + (size_t)li*65536, WqkvT + (size_t)li*768*256 + 131072, 256, 256);
        transpose_bf16<<<dim3(4, 4), 256, 0, stream>>>(Wm + (size_t)li*65536, WmT + (size_t)li*65536, 256, 256);
        transpose_bf16<<<dim3(8, 8), 256, 0, stream>>>(W1 + (size_t)li*262144, W1T + (size_t)li*262144, 512, 512);
        transpose_bf16<<<dim3(8, 4), 256, 0, stream>>>(W2 + (size_t)li*131072, W2T + (size_t)li*131072, 512, 256);
    }

    init_kernel<<<8192, 256, 0, stream>>>(feat, x, xm);
    route_kernel<<<8192, 256, 0, stream>>>(feat, fc, seg);

    for (int li = 0; li < NL; ++li) {
        const unsigned short* wqkv = WqkvT + (size_t)li * 768 * 256;
        const unsigned short* wm   = WmT + (size_t)li * 65536;
        const unsigned short* w1   = W1T + (size_t)li * 262144;
        const unsigned short* w2   = W2T + (size_t)li * 131072;

        // Q,K (elu+1) and V : one fused GEMM, N=768, bf16 outs
        mfma_gemm<256, 512, 1><<<dim3(256, 6), 256, 0, stream>>>(xm, wqkv, Qb, Kb, Vb);

        // KV/Ksum: per-segment partials (2x128 tokens per block, LDS merge), then tree reduce
        kv_kernel<<<BATCH * NHEAD * KVSEG, 512, 0, stream>>>(Kb, Vb, seg, part);
        kv_reduce<<<BATCH * NHEAD * KCLS, 256, 0, stream>>>(part, KV, Ks);

        // msgb (bf16) <- attention message
        msg_kernel<<<M_TOK, 256, 0, stream>>>(Qb, KV, Ks, seg, msgb);

        // xm[:,256:512] <- bf16(LN1(msg @ Wm))    [fused]
        gemm_ln<256, 1><<<512, 256, 0, stream>>>(msgb, wm, g1 + li * DM, b1 + li * DM, nullptr, xm);

        // hb (bf16 [M][512]) <- relu(concat(x,m1) @ W1)
        mfma_gemm<512, 512, 2><<<dim3(256, 4), 256, 0, stream>>>(xm, w1, hb, nullptr, nullptr);

        // x += LN2(h @ W2); xm[:,0:256] <- bf16(x)   [fused]
        gemm_ln<512, 2><<<512, 256, 0, stream>>>(hb, w2, g2 + li * DM, b2 + li * DM, x, xm);
    }
}

// Round 6
// 1037.911 us; speedup vs baseline: 3.6526x; 1.0915x over previous
//
#include <hip/hip_runtime.h>
#include <hip/hip_bf16.h>
#include <math.h>

#define DM 256
#define NHEAD 8
#define HD 32
#define NL 4
#define BATCH 8
#define SEQ 4096
#define KCLS 10
#define M_TOK (BATCH*SEQ)   // 32768

#define BM 128
#define BN 128
#define BKG 64

#define KVSEG 16
#define PART_STRIDE (KCLS * 1056)   // per-block partial: 10 clusters x (1024 KV + 32 Ks)

using bf16x8 = __attribute__((ext_vector_type(8))) short;
using f32x4  = __attribute__((ext_vector_type(4))) float;

__device__ __forceinline__ unsigned short f2bf(float f) {
    __hip_bfloat16 b = __float2bfloat16(f);
    return __builtin_bit_cast(unsigned short, b);
}
__device__ __forceinline__ float bf2f(unsigned short u) {
    unsigned v = (unsigned)u << 16;
    return __builtin_bit_cast(float, v);
}

__device__ __forceinline__ float wave_reduce_sum(float v) {
    #pragma unroll
    for (int off = 32; off > 0; off >>= 1) v += __shfl_xor(v, off, 64);
    return v;
}

// ---------------- init: x = feat (fp32), xm[:,0:256] = bf16(feat) ----------------
__global__ __launch_bounds__(256) void init_kernel(const float* __restrict__ feat,
                                                   float* __restrict__ x,
                                                   unsigned short* __restrict__ xm) {
    int i = blockIdx.x * 256 + threadIdx.x;      // over M_TOK*64 quads
    int row = i >> 6, c4 = (i & 63) * 4;
    float4 v = *(const float4*)(feat + (size_t)row * DM + c4);
    *(float4*)(x + (size_t)row * DM + c4) = v;
    ushort4 u; u.x = f2bf(v.x); u.y = f2bf(v.y); u.z = f2bf(v.z); u.w = f2bf(v.w);
    *(ushort4*)(xm + (size_t)row * 512 + c4) = u;
}

// ---------------- routing ----------------
__global__ void route_kernel(const float* __restrict__ x, const float* __restrict__ fc,
                             int* __restrict__ seg) {
    int wid = (int)((blockIdx.x * (size_t)blockDim.x + threadIdx.x) >> 6);
    int lane = threadIdx.x & 63;
    if (wid >= M_TOK) return;
    int b = wid / SEQ;
    float4 xv = *(const float4*)(x + (size_t)wid * DM + lane * 4);
    float nb2 = xv.x*xv.x + xv.y*xv.y + xv.z*xv.z + xv.w*xv.w;
    nb2 = wave_reduce_sum(nb2);
    float nb = sqrtf(nb2);
    float best = -1e30f; int bestk = 0;
    for (int k = 0; k < KCLS; ++k) {
        float4 fv = *(const float4*)(fc + ((size_t)(b * KCLS + k)) * DM + lane * 4);
        float d = fv.x*xv.x + fv.y*xv.y + fv.z*xv.z + fv.w*xv.w;
        float n = fv.x*fv.x + fv.y*fv.y + fv.z*fv.z + fv.w*fv.w;
        d = wave_reduce_sum(d);
        n = wave_reduce_sum(n);
        float sim = d / fmaxf(sqrtf(n) * nb, 1e-8f);
        if (sim > best) { best = sim; bestk = k; }
    }
    if (lane == 0) seg[wid] = bestk;
}

// ---------------- deterministic cluster counting-sort (per batch) ----------------
// A) per-(b,chunk) cluster counts via ballot
__global__ __launch_bounds__(256) void seg_count(const int* __restrict__ seg,
                                                 int* __restrict__ cnt) {
    __shared__ int wc[4][KCLS];
    int b = blockIdx.x >> 4, chunk = blockIdx.x & 15;
    int t = threadIdx.x, w = t >> 6, lane = t & 63;
    int c = seg[b * SEQ + chunk * 256 + t];
    #pragma unroll
    for (int cc = 0; cc < KCLS; ++cc) {
        unsigned long long m = __ballot(c == cc);
        if (lane == 0) wc[w][cc] = __popcll(m);
    }
    __syncthreads();
    if (t < KCLS)
        cnt[(b * 16 + chunk) * KCLS + t] = wc[0][t] + wc[1][t] + wc[2][t] + wc[3][t];
}

// B) scan: chunkbase[b][chunk][c] = cluster base + prefix over chunks
__global__ __launch_bounds__(128) void seg_scan(const int* __restrict__ cnt,
                                                int* __restrict__ chunkbase) {
    __shared__ int tot[BATCH][KCLS];
    int tid = threadIdx.x;
    if (tid < BATCH * KCLS) {
        int b = tid / KCLS, c = tid % KCLS;
        int cb[16];
        int run = 0;
        #pragma unroll
        for (int j = 0; j < 16; ++j) {
            cb[j] = run;
            run += cnt[(b * 16 + j) * KCLS + c];
        }
        tot[b][c] = run;
        __syncthreads();
        int base = 0;
        for (int cp = 0; cp < c; ++cp) base += tot[b][cp];
        #pragma unroll
        for (int j = 0; j < 16; ++j)
            chunkbase[(b * 16 + j) * KCLS + c] = cb[j] + base;
    } else {
        __syncthreads();
    }
}

// C) scatter: pidx[b][pos] = token, psegs[b][pos] = cluster (deterministic ranks)
__global__ __launch_bounds__(256) void seg_scatter(const int* __restrict__ seg,
                                                   const int* __restrict__ chunkbase,
                                                   int* __restrict__ pidx,
                                                   int* __restrict__ psegs) {
    __shared__ int wc[4][KCLS];
    int b = blockIdx.x >> 4, chunk = blockIdx.x & 15;
    int t = threadIdx.x, w = t >> 6, lane = t & 63;
    int l = chunk * 256 + t;
    int c = seg[b * SEQ + l];
    int rank_w = 0;
    #pragma unroll
    for (int cc = 0; cc < KCLS; ++cc) {
        unsigned long long m = __ballot(c == cc);
        if (lane == 0) wc[w][cc] = __popcll(m);
        if (cc == c) rank_w = __popcll(m & ((1ULL << lane) - 1ULL));
    }
    __syncthreads();
    int rank = rank_w;
    for (int wp = 0; wp < 4; ++wp)
        if (wp < w) rank += wc[wp][c];
    int pos = chunkbase[(b * 16 + chunk) * KCLS + c] + rank;
    pidx[b * SEQ + pos] = l;
    psegs[b * SEQ + pos] = c;
}

// ---------------- weight transpose+convert: src [K][N] fp32 -> dst [N][K] bf16 ----------------
__global__ __launch_bounds__(256) void transpose_bf16(const float* __restrict__ src,
                                                      unsigned short* __restrict__ dst,
                                                      int K, int N) {
    __shared__ float s[64][65];
    int k0 = blockIdx.x * 64, n0 = blockIdx.y * 64;
    int t = threadIdx.x;
    int r = t >> 4, c4 = (t & 15) * 4;
    #pragma unroll
    for (int i = 0; i < 4; ++i) {
        float4 v = *(const float4*)(src + (size_t)(k0 + r + i*16) * N + n0 + c4);
        s[c4+0][r+i*16] = v.x; s[c4+1][r+i*16] = v.y;
        s[c4+2][r+i*16] = v.z; s[c4+3][r+i*16] = v.w;
    }
    __syncthreads();
    #pragma unroll
    for (int i = 0; i < 4; ++i) {
        int nr = r + i*16;
        ushort4 u;
        u.x = f2bf(s[nr][c4+0]); u.y = f2bf(s[nr][c4+1]);
        u.z = f2bf(s[nr][c4+2]); u.w = f2bf(s[nr][c4+3]);
        *(ushort4*)(dst + (size_t)(n0 + nr) * K + k0 + c4) = u;
    }
}

// ---------------- bf16 MFMA GEMM (128x128 tile): out = act( A[M,KD] * Bt[N,KD]^T ) ----------------
// MODE 1: QKV (N=768): bf16 outs: cols 0-255 -> Ob0 (elu+1), 256-511 -> Ob1 (elu+1), 512-767 -> Ob2
// MODE 2: W1 (N=512): bf16 out Ob0 [M][512], relu
template<int KD, int AS, int MODE>
__global__ __launch_bounds__(256) void mfma_gemm(
    const unsigned short* __restrict__ A, const unsigned short* __restrict__ Bt,
    unsigned short* __restrict__ Ob0, unsigned short* __restrict__ Ob1,
    unsigned short* __restrict__ Ob2)
{
    __shared__ unsigned short As[BM * BKG];
    __shared__ unsigned short Bs[BN * BKG];
    int t = threadIdx.x;
    int lane = t & 63;
    int w = t >> 6;
    int wm = w & 1, wn = w >> 1;         // 2x2 wave grid, each wave 64x64
    int bm = blockIdx.x * BM;
    int bn = blockIdx.y * BN;

    f32x4 acc[4][4];
    #pragma unroll
    for (int m = 0; m < 4; ++m)
        #pragma unroll
        for (int n = 0; n < 4; ++n)
            acc[m][n] = (f32x4){0.f, 0.f, 0.f, 0.f};

    for (int k0 = 0; k0 < KD; k0 += BKG) {
        #pragma unroll
        for (int i = 0; i < 4; ++i) {
            int chunk = i * 256 + t;
            int row = chunk >> 3, cc = chunk & 7;
            __builtin_amdgcn_global_load_lds(
                (const __attribute__((address_space(1))) void*)(A + (size_t)(bm + row) * AS + k0 + cc * 8),
                (__attribute__((address_space(3))) void*)((char*)As + chunk * 16), 16, 0, 0);
            __builtin_amdgcn_global_load_lds(
                (const __attribute__((address_space(1))) void*)(Bt + (size_t)(bn + row) * KD + k0 + cc * 8),
                (__attribute__((address_space(3))) void*)((char*)Bs + chunk * 16), 16, 0, 0);
        }
        asm volatile("s_waitcnt vmcnt(0)");
        __syncthreads();
        #pragma unroll
        for (int kk = 0; kk < 2; ++kk) {
            int kbyte = (kk * 32 + (lane >> 4) * 8) * 2;
            bf16x8 af[4], bfr[4];
            #pragma unroll
            for (int m = 0; m < 4; ++m)
                af[m] = *(const bf16x8*)((const char*)As + (wm*64 + m*16 + (lane & 15)) * 128 + kbyte);
            #pragma unroll
            for (int n = 0; n < 4; ++n)
                bfr[n] = *(const bf16x8*)((const char*)Bs + (wn*64 + n*16 + (lane & 15)) * 128 + kbyte);
            #pragma unroll
            for (int m = 0; m < 4; ++m)
                #pragma unroll
                for (int n = 0; n < 4; ++n)
                    acc[m][n] = __builtin_amdgcn_mfma_f32_16x16x32_bf16(af[m], bfr[n], acc[m][n], 0, 0, 0);
        }
        __syncthreads();
    }

    int row0 = bm + wm * 64 + (lane >> 4) * 4;
    int lcol = wn * 64 + (lane & 15);
    if (MODE == 1) {
        unsigned short* Obuf = (bn < 256) ? Ob0 : (bn < 512) ? Ob1 : Ob2;
        const bool act = (bn < 512);
        int cc0 = (bn & 255) + lcol;
        #pragma unroll
        for (int m = 0; m < 4; ++m)
            #pragma unroll
            for (int n = 0; n < 4; ++n)
                #pragma unroll
                for (int j = 0; j < 4; ++j) {
                    float v = acc[m][n][j];
                    if (act) v = (v > 0.f) ? v + 1.f : expf(v);
                    Obuf[(size_t)(row0 + m*16 + j) * 256 + cc0 + n*16] = f2bf(v);
                }
    } else {
        #pragma unroll
        for (int m = 0; m < 4; ++m)
            #pragma unroll
            for (int n = 0; n < 4; ++n)
                #pragma unroll
                for (int j = 0; j < 4; ++j)
                    Ob0[(size_t)(row0 + m*16 + j) * 512 + bn + lcol + n*16] =
                        f2bf(fmaxf(acc[m][n][j], 0.f));
    }
}

// ---------------- fused GEMM + LayerNorm (full rows per block: BM=64, BN=256) ----------------
// LNMODE 1: xm[:,256:512] = bf16( LN(A@Bt^T, g, b) )
// LNMODE 2: x += LN(A@Bt^T, g, b); xm[:,0:256] = bf16(x)
template<int KD, int LNMODE>
__global__ __launch_bounds__(256) void gemm_ln(
    const unsigned short* __restrict__ A, const unsigned short* __restrict__ Bt,
    const float* __restrict__ g, const float* __restrict__ bb,
    float* __restrict__ x, unsigned short* __restrict__ xm)
{
    __shared__ unsigned short As[64 * BKG];
    __shared__ unsigned short Bs[256 * BKG];
    __shared__ float redS[4][64];
    __shared__ float redQ[4][64];
    int t = threadIdx.x;
    int lane = t & 63;
    int w = t >> 6;                      // wave covers cols [w*64, w*64+64)
    int li = lane & 15, lg = lane >> 4;
    int bm = blockIdx.x * 64;

    f32x4 acc[4][4];
    #pragma unroll
    for (int m = 0; m < 4; ++m)
        #pragma unroll
        for (int n = 0; n < 4; ++n)
            acc[m][n] = (f32x4){0.f, 0.f, 0.f, 0.f};

    for (int k0 = 0; k0 < KD; k0 += BKG) {
        #pragma unroll
        for (int i = 0; i < 2; ++i) {
            int chunk = i * 256 + t;
            int row = chunk >> 3, cc = chunk & 7;
            __builtin_amdgcn_global_load_lds(
                (const __attribute__((address_space(1))) void*)(A + (size_t)(bm + row) * KD + k0 + cc * 8),
                (__attribute__((address_space(3))) void*)((char*)As + chunk * 16), 16, 0, 0);
        }
        #pragma unroll
        for (int i = 0; i < 8; ++i) {
            int chunk = i * 256 + t;
            int row = chunk >> 3, cc = chunk & 7;
            __builtin_amdgcn_global_load_lds(
                (const __attribute__((address_space(1))) void*)(Bt + (size_t)row * KD + k0 + cc * 8),
                (__attribute__((address_space(3))) void*)((char*)Bs + chunk * 16), 16, 0, 0);
        }
        asm volatile("s_waitcnt vmcnt(0)");
        __syncthreads();
        #pragma unroll
        for (int kk = 0; kk < 2; ++kk) {
            int kbyte = (kk * 32 + lg * 8) * 2;
            bf16x8 af[4], bfr[4];
            #pragma unroll
            for (int m = 0; m < 4; ++m)
                af[m] = *(const bf16x8*)((const char*)As + (m*16 + li) * 128 + kbyte);
            #pragma unroll
            for (int n = 0; n < 4; ++n)
                bfr[n] = *(const bf16x8*)((const char*)Bs + (w*64 + n*16 + li) * 128 + kbyte);
            #pragma unroll
            for (int m = 0; m < 4; ++m)
                #pragma unroll
                for (int n = 0; n < 4; ++n)
                    acc[m][n] = __builtin_amdgcn_mfma_f32_16x16x32_bf16(af[m], bfr[n], acc[m][n], 0, 0, 0);
        }
        __syncthreads();
    }

    // ---- row-wise LN over 256 cols (4 waves x 64 cols) ----
    float vs[4][4], vq[4][4];
    #pragma unroll
    for (int m = 0; m < 4; ++m)
        #pragma unroll
        for (int j = 0; j < 4; ++j) {
            float s = 0.f, q = 0.f;
            #pragma unroll
            for (int n = 0; n < 4; ++n) {
                float v = acc[m][n][j];
                s += v; q += v * v;
            }
            #pragma unroll
            for (int msk = 1; msk < 16; msk <<= 1) {
                s += __shfl_xor(s, msk, 64);
                q += __shfl_xor(q, msk, 64);
            }
            vs[m][j] = s; vq[m][j] = q;
        }
    if (li == 0) {
        #pragma unroll
        for (int m = 0; m < 4; ++m)
            #pragma unroll
            for (int j = 0; j < 4; ++j) {
                redS[w][m*16 + lg*4 + j] = vs[m][j];
                redQ[w][m*16 + lg*4 + j] = vq[m][j];
            }
    }
    __syncthreads();

    float gv[4], bv[4];
    #pragma unroll
    for (int n = 0; n < 4; ++n) {
        int col = w*64 + n*16 + li;
        gv[n] = g[col]; bv[n] = bb[col];
    }
    #pragma unroll
    for (int m = 0; m < 4; ++m)
        #pragma unroll
        for (int j = 0; j < 4; ++j) {
            int r = m*16 + lg*4 + j;
            float S = redS[0][r] + redS[1][r] + redS[2][r] + redS[3][r];
            float Q = redQ[0][r] + redQ[1][r] + redQ[2][r] + redQ[3][r];
            float mu = S * (1.f / 256.f);
            float var = Q * (1.f / 256.f) - mu * mu;
            float rs = rsqrtf(var + 1e-5f);
            #pragma unroll
            for (int n = 0; n < 4; ++n) {
                int col = w*64 + n*16 + li;
                float o = gv[n] * (acc[m][n][j] - mu) * rs + bv[n];
                if (LNMODE == 1) {
                    xm[(size_t)(bm + r) * 512 + 256 + col] = f2bf(o);
                } else {
                    size_t idx = (size_t)(bm + r) * 256 + col;
                    float xv = x[idx] + o;
                    x[idx] = xv;
                    xm[(size_t)(bm + r) * 512 + col] = f2bf(xv);
                }
            }
        }
}

// ---------------- KV / Ksum partials over cluster-sorted gathered tokens ----------------
// Single live accumulator; flush to LDS slab on (rare, block-uniform) cluster change.
__global__ __launch_bounds__(256) void kv_kernel(
    const unsigned short* __restrict__ Kf, const unsigned short* __restrict__ V,
    const int* __restrict__ pidx, const int* __restrict__ psegs,
    float* __restrict__ part)
{
    __shared__ float mg[KCLS * 1056];
    __shared__ int sIdx[256];
    __shared__ int sSeg[256];
    int blk = blockIdx.x;
    int s = blk & (KVSEG - 1);
    int bh = blk / KVSEG;
    int b = bh >> 3, h = bh & 7;
    int t = threadIdx.x;
    int d = t >> 3, e0 = (t & 7) * 4;

    for (int i = t; i < KCLS * 1056; i += 256) mg[i] = 0.f;
    sIdx[t] = pidx[b * SEQ + s * 256 + t];
    sSeg[t] = psegs[b * SEQ + s * 256 + t];
    __syncthreads();

    const unsigned short* Kp = Kf + (size_t)(b * SEQ) * DM + h * HD + d;
    const unsigned short* Vp = V  + (size_t)(b * SEQ) * DM + h * HD + e0;

    float4 a = {0.f, 0.f, 0.f, 0.f};
    float ks = 0.f;
    int ccur = __builtin_amdgcn_readfirstlane(sSeg[0]);

    for (int l0 = 0; l0 < 256; l0 += 8) {
        int idxv[8], csegv[8];
        #pragma unroll
        for (int u = 0; u < 8; ++u) { idxv[u] = sIdx[l0 + u]; csegv[u] = sSeg[l0 + u]; }
        unsigned short ku[8]; ushort4 vu[8];
        #pragma unroll
        for (int u = 0; u < 8; ++u) {
            size_t off = (size_t)idxv[u] * DM;
            ku[u] = Kp[off];
            vu[u] = *(const ushort4*)(Vp + off);
        }
        #pragma unroll
        for (int u = 0; u < 8; ++u) {
            int c = __builtin_amdgcn_readfirstlane(csegv[u]);
            if (c != ccur) {
                *(float4*)(mg + ccur * 1056 + d * 32 + e0) = a;
                if ((t & 7) == 0) mg[ccur * 1056 + 1024 + d] = ks;
                a = (float4){0.f, 0.f, 0.f, 0.f};
                ks = 0.f;
                ccur = c;
            }
            float kd = bf2f(ku[u]);
            float4 v4;
            v4.x = bf2f(vu[u].x); v4.y = bf2f(vu[u].y);
            v4.z = bf2f(vu[u].z); v4.w = bf2f(vu[u].w);
            a.x = fmaf(kd, v4.x, a.x); a.y = fmaf(kd, v4.y, a.y);
            a.z = fmaf(kd, v4.z, a.z); a.w = fmaf(kd, v4.w, a.w);
            ks += kd;
        }
    }
    *(float4*)(mg + ccur * 1056 + d * 32 + e0) = a;
    if ((t & 7) == 0) mg[ccur * 1056 + 1024 + d] = ks;
    __syncthreads();

    float* pb = part + (size_t)blk * PART_STRIDE;
    for (int i = t; i < (KCLS * 1056) / 4; i += 256) {
        float4 v = *(const float4*)(mg + i * 4);
        *(float4*)(pb + i * 4) = v;
    }
}

// ---------------- reduce partials -> KV, Ks ----------------
__global__ __launch_bounds__(256) void kv_reduce(
    const float* __restrict__ part, float* __restrict__ KV, float* __restrict__ Ks)
{
    int blk = blockIdx.x;          // bh * KCLS + c
    int c = blk % KCLS;
    int bh = blk / KCLS;
    int b = bh >> 3, h = bh & 7;
    int t = threadIdx.x;
    const float* pb = part + (size_t)bh * KVSEG * PART_STRIDE + c * 1056;
    float4 acc = {0, 0, 0, 0};
    float ka = 0.f;
    #pragma unroll
    for (int s = 0; s < KVSEG; ++s) {
        float4 v = *(const float4*)(pb + (size_t)s * PART_STRIDE + t * 4);
        acc.x += v.x; acc.y += v.y; acc.z += v.z; acc.w += v.w;
        if (t < 32) ka += pb[(size_t)s * PART_STRIDE + 1024 + t];
    }
    *(float4*)(KV + ((size_t)(b * KCLS + c) * NHEAD + h) * HD * HD + t * 4) = acc;
    if (t < 32) Ks[((size_t)(b * KCLS + c) * NHEAD + h) * HD + t] = ka;
}

// ---------------- per-token message (bf16 Q in), 8 tokens per block -> bf16 ----------------
__global__ __launch_bounds__(256) void msg_kernel(
    const unsigned short* __restrict__ Q, const float* __restrict__ KV,
    const float* __restrict__ Ks, const int* __restrict__ seg,
    unsigned short* __restrict__ msgb)
{
    __shared__ float sQ[8][DM];
    int tok0 = blockIdx.x * 8;
    int t = threadIdx.x;
    int h = t >> 5, e = t & 31;
    #pragma unroll
    for (int tk = 0; tk < 8; ++tk)
        sQ[tk][t] = bf2f(Q[(size_t)(tok0 + tk) * DM + t]);
    __syncthreads();
    int b = tok0 / SEQ;
    #pragma unroll
    for (int tk = 0; tk < 8; ++tk) {
        int tokn = tok0 + tk;
        int c = seg[tokn];
        const float* kvp = KV + ((size_t)(b * KCLS + c) * NHEAD + h) * HD * HD;
        const float* ksp = Ks + ((size_t)(b * KCLS + c) * NHEAD + h) * HD;
        float macc = 0.f, zacc = 0.f;
        #pragma unroll
        for (int dd = 0; dd < 32; ++dd) {
            float qd = sQ[tk][h * 32 + dd];
            macc = fmaf(qd, kvp[dd * 32 + e], macc);
            zacc = fmaf(qd, ksp[dd], zacc);
        }
        msgb[(size_t)tokn * DM + t] = f2bf(macc / (zacc + 1e-6f));
    }
}

extern "C" void kernel_launch(void* const* d_in, const int* in_sizes, int n_in,
                              void* d_out, int out_size, void* d_ws, size_t ws_size,
                              hipStream_t stream)
{
    const float* feat = (const float*)d_in[1];
    const float* fc   = (const float*)d_in[2];
    const float* Wq   = (const float*)d_in[3];
    const float* Wk   = (const float*)d_in[4];
    const float* Wv   = (const float*)d_in[5];
    const float* Wm   = (const float*)d_in[6];
    const float* W1   = (const float*)d_in[7];
    const float* W2   = (const float*)d_in[8];
    const float* g1   = (const float*)d_in[9];
    const float* b1   = (const float*)d_in[10];
    const float* g2   = (const float*)d_in[11];
    const float* b2   = (const float*)d_in[12];
    float* x = (float*)d_out;

    char* ws = (char*)d_ws;
    auto alloc = [&](size_t bytes) { char* p = ws; ws += (bytes + 255) & ~(size_t)255; return p; };
    int*   seg   = (int*)  alloc((size_t)M_TOK * 4);
    int*   cnt   = (int*)  alloc((size_t)BATCH * 16 * KCLS * 4);
    int*   cbase = (int*)  alloc((size_t)BATCH * 16 * KCLS * 4);
    int*   pidx  = (int*)  alloc((size_t)M_TOK * 4);
    int*   psegs = (int*)  alloc((size_t)M_TOK * 4);
    float* KV    = (float*)alloc((size_t)BATCH * KCLS * NHEAD * HD * HD * 4);
    float* Ks    = (float*)alloc((size_t)BATCH * KCLS * NHEAD * HD * 4);
    float* part  = (float*)alloc((size_t)BATCH * NHEAD * KVSEG * PART_STRIDE * 4);
    unsigned short* xm = (unsigned short*)alloc((size_t)M_TOK * 512 * 2);
    char* bufA = alloc((size_t)M_TOK * 512 * 2);   // Qb bf16 [M][256] then hb bf16 [M][512]
    char* bufB = alloc((size_t)M_TOK * 256 * 2);   // Kb bf16
    char* bufC = alloc((size_t)M_TOK * 256 * 2);   // Vb bf16 then msgb bf16
    unsigned short* WqkvT = (unsigned short*)alloc((size_t)NL * 768 * 256 * 2);
    unsigned short* WmT   = (unsigned short*)alloc((size_t)NL * 256 * 256 * 2);
    unsigned short* W1T   = (unsigned short*)alloc((size_t)NL * 512 * 512 * 2);
    unsigned short* W2T   = (unsigned short*)alloc((size_t)NL * 256 * 512 * 2);

    unsigned short* Qb = (unsigned short*)bufA;
    unsigned short* hb = (unsigned short*)bufA;
    unsigned short* Kb = (unsigned short*)bufB;
    unsigned short* Vb = (unsigned short*)bufC;
    unsigned short* msgb = (unsigned short*)bufC;

    // weight transpose+convert (per launch; small)
    for (int li = 0; li < NL; ++li) {
        transpose_bf16<<<dim3(4, 4), 256, 0, stream>>>(Wq + (size_t)li*65536, WqkvT + (size_t)li*768*256, 256, 256);
        transpose_bf16<<<dim3(4, 4), 256, 0, stream>>>(Wk + (size_t)li*65536, WqkvT + (size_t)li*768*256 + 65536, 256, 256);
        transpose_bf16<<<dim3(4, 4), 256, 0, stream>>>(Wv + (size_t)li*65536, WqkvT + (size_t)li*768*256 + 131072, 256, 256);
        transpose_bf16<<<dim3(4, 4), 256, 0, stream>>>(Wm + (size_t)li*65536, WmT + (size_t)li*65536, 256, 256);
        transpose_bf16<<<dim3(8, 8), 256, 0, stream>>>(W1 + (size_t)li*262144, W1T + (size_t)li*262144, 512, 512);
        transpose_bf16<<<dim3(8, 4), 256, 0, stream>>>(W2 + (size_t)li*131072, W2T + (size_t)li*131072, 512, 256);
    }

    init_kernel<<<8192, 256, 0, stream>>>(feat, x, xm);
    route_kernel<<<8192, 256, 0, stream>>>(feat, fc, seg);

    // deterministic cluster-sorted permutation (once; reused by all layers)
    seg_count<<<BATCH * 16, 256, 0, stream>>>(seg, cnt);
    seg_scan<<<1, 128, 0, stream>>>(cnt, cbase);
    seg_scatter<<<BATCH * 16, 256, 0, stream>>>(seg, cbase, pidx, psegs);

    for (int li = 0; li < NL; ++li) {
        const unsigned short* wqkv = WqkvT + (size_t)li * 768 * 256;
        const unsigned short* wm   = WmT + (size_t)li * 65536;
        const unsigned short* w1   = W1T + (size_t)li * 262144;
        const unsigned short* w2   = W2T + (size_t)li * 131072;

        // Q,K (elu+1) and V : one fused GEMM, N=768, bf16 outs
        mfma_gemm<256, 512, 1><<<dim3(256, 6), 256, 0, stream>>>(xm, wqkv, Qb, Kb, Vb);

        // KV/Ksum: sorted-gather partials, then tree reduce
        kv_kernel<<<BATCH * NHEAD * KVSEG, 256, 0, stream>>>(Kb, Vb, pidx, psegs, part);
        kv_reduce<<<BATCH * NHEAD * KCLS, 256, 0, stream>>>(part, KV, Ks);

        // msgb (bf16) <- attention message
        msg_kernel<<<M_TOK / 8, 256, 0, stream>>>(Qb, KV, Ks, seg, msgb);

        // xm[:,256:512] <- bf16(LN1(msg @ Wm))    [fused]
        gemm_ln<256, 1><<<512, 256, 0, stream>>>(msgb, wm, g1 + li * DM, b1 + li * DM, nullptr, xm);

        // hb (bf16 [M][512]) <- relu(concat(x,m1) @ W1)
        mfma_gemm<512, 512, 2><<<dim3(256, 4), 256, 0, stream>>>(xm, w1, hb, nullptr, nullptr);

        // x += LN2(h @ W2); xm[:,0:256] <- bf16(x)   [fused]
        gemm_ln<512, 2><<<512, 256, 0, stream>>>(hb, w2, g2 + li * DM, b2 + li * DM, x, xm);
    }
}